// Round 2
// baseline (669.768 us; speedup 1.0000x reference)
//
#include <hip/hip_runtime.h>
#include <stdint.h>
#include <math.h>

#define TB 2048
#define CD 1024
#define NH 16
#define NB 4

typedef short s16x8 __attribute__((ext_vector_type(8)));
typedef unsigned short u16x4 __attribute__((ext_vector_type(4)));
typedef float f32x4 __attribute__((ext_vector_type(4)));

__device__ __forceinline__ unsigned short f2bf(float f) {
    union { float f; uint32_t u; } v; v.f = f;
    return (unsigned short)((v.u + 0x7fffu + ((v.u >> 16) & 1u)) >> 16);
}

// ---------------- cast fp32 -> bf16 (vectorized x4) ----------------
__global__ void cast_k(const float* __restrict__ src, unsigned short* __restrict__ dst, int n4) {
    int i = blockIdx.x * blockDim.x + threadIdx.x;
    if (i < n4) {
        float4 v = reinterpret_cast<const float4*>(src)[i];
        u16x4 o = { f2bf(v.x), f2bf(v.y), f2bf(v.z), f2bf(v.w) };
        reinterpret_cast<u16x4*>(dst)[i] = o;
    }
}

// ---------------- GEMM C = A(M,K) * Bw(N,K)^T ----------------
// MODE 0: A = x_bf16 (8192x1024), Bw = [wq;wk;wv] (3072x1024)
//         writes q,k (B,H,T,HD) bf16 and v transposed (B,H,HD,T) bf16, + bias
// MODE 1: A = attn_out (8192x1024), Bw = wp (1024x1024)
//         writes fp32 out (B,T,C) + bias
template<int MODE>
__launch_bounds__(256)
__global__ void gemm_bt(const unsigned short* __restrict__ A,
                        const unsigned short* __restrict__ Bw,
                        unsigned short* __restrict__ qo,
                        unsigned short* __restrict__ ko,
                        unsigned short* __restrict__ vto,
                        const float* __restrict__ b0,
                        const float* __restrict__ b1,
                        const float* __restrict__ b2,
                        float* __restrict__ fout,
                        const float* __restrict__ bp)
{
    __shared__ unsigned short As[128 * 40];  // pad stride 40 -> 2-way (free) bank pattern
    __shared__ unsigned short Bs[128 * 40];
    const int tid = threadIdx.x;
    const int mbase = blockIdx.y * 128;
    const int nbase = blockIdx.x * 128;
    const int lane = tid & 63;
    const int w = tid >> 6;
    const int g = lane >> 4;
    const int lr = lane & 15;
    const int wm = (w >> 1) * 64;
    const int wn = (w & 1) * 64;
    const int row_l = tid >> 2;       // 0..63
    const int col8 = (tid & 3) * 8;   // 0,8,16,24

    f32x4 acc[4][4];
#pragma unroll
    for (int i = 0; i < 4; ++i)
#pragma unroll
        for (int j = 0; j < 4; ++j) acc[i][j] = (f32x4)0.0f;

    for (int k0 = 0; k0 < 1024; k0 += 32) {
        __syncthreads();   // protect previous iteration's reads
#pragma unroll
        for (int p = 0; p < 2; ++p) {
            const int r = row_l + p * 64;
            *reinterpret_cast<s16x8*>(&As[r * 40 + col8]) =
                *reinterpret_cast<const s16x8*>(A + (size_t)(mbase + r) * 1024 + k0 + col8);
            *reinterpret_cast<s16x8*>(&Bs[r * 40 + col8]) =
                *reinterpret_cast<const s16x8*>(Bw + (size_t)(nbase + r) * 1024 + k0 + col8);
        }
        __syncthreads();
        s16x8 af[4], bfv[4];
#pragma unroll
        for (int mi = 0; mi < 4; ++mi)
            af[mi] = *reinterpret_cast<const s16x8*>(&As[(wm + mi * 16 + lr) * 40 + g * 8]);
#pragma unroll
        for (int ni = 0; ni < 4; ++ni)
            bfv[ni] = *reinterpret_cast<const s16x8*>(&Bs[(wn + ni * 16 + lr) * 40 + g * 8]);
#pragma unroll
        for (int mi = 0; mi < 4; ++mi)
#pragma unroll
            for (int ni = 0; ni < 4; ++ni)
                acc[mi][ni] = __builtin_amdgcn_mfma_f32_16x16x32_bf16(af[mi], bfv[ni], acc[mi][ni], 0, 0, 0);
    }

    // epilogue: D[row=g*4+r][col=lr] per 16x16 tile
#pragma unroll
    for (int mi = 0; mi < 4; ++mi) {
        const int mg = mbase + wm + mi * 16 + g * 4;   // +r ; multiple of 4
#pragma unroll
        for (int ni = 0; ni < 4; ++ni) {
            const int ng = nbase + wn + ni * 16 + lr;
            if constexpr (MODE == 0) {
                const int which = ng >> 10;
                const int nin = ng & 1023;
                const float bias = (which == 0) ? b0[nin] : (which == 1) ? b1[nin] : b2[nin];
                const int h = nin >> 6, d = nin & 63;
                const int b = mg >> 11, t = mg & 2047;
                if (which == 2) {
                    // v transposed: vto[((b*16+h)*64 + d)*2048 + t..t+3]
                    u16x4 pv = { f2bf(acc[mi][ni][0] + bias), f2bf(acc[mi][ni][1] + bias),
                                 f2bf(acc[mi][ni][2] + bias), f2bf(acc[mi][ni][3] + bias) };
                    *reinterpret_cast<u16x4*>(vto + ((size_t)((b * 16 + h) * 64 + d)) * 2048 + t) = pv;
                } else {
                    unsigned short* dst = (which == 0) ? qo : ko;
#pragma unroll
                    for (int r = 0; r < 4; ++r)
                        dst[((size_t)(b * 16 + h) * 2048 + (t + r)) * 64 + d] = f2bf(acc[mi][ni][r] + bias);
                }
            } else {
                const float bias = bp[ng];
#pragma unroll
                for (int r = 0; r < 4; ++r)
                    fout[(size_t)(mg + r) * 1024 + ng] = acc[mi][ni][r] + bias;
            }
        }
    }
}

// ---------------- flash attention (S^T formulation) ----------------
// grid: (32 qblocks, 64 bh); block 256 = 4 waves, each wave owns 16 q-rows.
// Computes S^T = K*Q^T via mfma so each lane owns q-column (lane&15):
// softmax reduce = 8 local + 2 shfl_xor. PV as O^T = V^T * P^T with V
// pre-transposed (contiguous fragment loads); P via per-wave LDS roundtrip.
__launch_bounds__(256)
__global__ void attn_k(const unsigned short* __restrict__ qg,
                       const unsigned short* __restrict__ kg,
                       const unsigned short* __restrict__ vtg,
                       unsigned short* __restrict__ og)
{
    __shared__ unsigned short P_lds[4][16 * 40];  // per-wave 16q x 32key (pad 40)
    const int qb = blockIdx.x;
    const int bh = blockIdx.y;
    const int b = bh >> 4;
    const int h = bh & 15;
    const int tid = threadIdx.x;
    const int w = tid >> 6;
    const int lane = tid & 63;
    const int g = lane >> 4;
    const int lr = lane & 15;
    const int qbase = qb * 64 + w * 16;
    const int q_idx = qbase + lr;          // this lane's q column

    const unsigned short* Qp = qg + (size_t)bh * TB * 64;
    const unsigned short* Kp = kg + (size_t)bh * TB * 64;
    const unsigned short* Vt = vtg + (size_t)bh * 64 * TB;

    // Q as B-operand: Q[qbase+lr][32t + 8g + j]
    s16x8 bq0 = *reinterpret_cast<const s16x8*>(Qp + (size_t)q_idx * 64 + g * 8);
    s16x8 bq1 = *reinterpret_cast<const s16x8*>(Qp + (size_t)q_idx * 64 + 32 + g * 8);

    f32x4 oacc[4];
#pragma unroll
    for (int i = 0; i < 4; ++i) oacc[i] = (f32x4)0.0f;
    float m_i = -INFINITY, l_i = 0.0f;
    const float scale = 0.02209708691207961f;  // 1/sqrt(2048) (ref scales by 1/sqrt(T))

    const int ktiles = (qbase + 16 + 31) >> 5;  // causal limit, per wave
    for (int kt = 0; kt < ktiles; ++kt) {
        const int k0 = kt * 32;
        // scores^T: two 16-key subtiles; D[row=key(g*4+r)][col=q(lr)]
        f32x4 st[2];
#pragma unroll
        for (int sub = 0; sub < 2; ++sub) {
            const unsigned short* kr = Kp + (size_t)(k0 + sub * 16 + lr) * 64 + g * 8;
            s16x8 ak0 = *reinterpret_cast<const s16x8*>(kr);
            s16x8 ak1 = *reinterpret_cast<const s16x8*>(kr + 32);
            f32x4 z = (f32x4)0.0f;
            z = __builtin_amdgcn_mfma_f32_16x16x32_bf16(ak0, bq0, z, 0, 0, 0);
            st[sub] = __builtin_amdgcn_mfma_f32_16x16x32_bf16(ak1, bq1, z, 0, 0, 0);
        }
        float s8[8];
        float mloc = -INFINITY;
#pragma unroll
        for (int sub = 0; sub < 2; ++sub)
#pragma unroll
            for (int r = 0; r < 4; ++r) {
                const int key = k0 + sub * 16 + g * 4 + r;
                float sv = st[sub][r] * scale;
                if (key > q_idx) sv = -INFINITY;
                s8[sub * 4 + r] = sv;
                mloc = fmaxf(mloc, sv);
            }
        mloc = fmaxf(mloc, __shfl_xor(mloc, 16));
        mloc = fmaxf(mloc, __shfl_xor(mloc, 32));
        const float m_new = fmaxf(m_i, mloc);
        const float alpha = __expf(m_i - m_new);
        float psum = 0.0f;
        unsigned short pb[8];
#pragma unroll
        for (int i = 0; i < 8; ++i) {
            const float p = __expf(s8[i] - m_new);
            psum += p;
            pb[i] = f2bf(p);
        }
        psum += __shfl_xor(psum, 16);
        psum += __shfl_xor(psum, 32);
        l_i = l_i * alpha + psum;
        m_i = m_new;
#pragma unroll
        for (int dt = 0; dt < 4; ++dt) oacc[dt] *= alpha;

        // P^T roundtrip: lane owns q=lr, keys {sub*16+4g..+3}; store into [q][key]
        u16x4 w0 = { pb[0], pb[1], pb[2], pb[3] };
        u16x4 w1 = { pb[4], pb[5], pb[6], pb[7] };
        *reinterpret_cast<u16x4*>(&P_lds[w][lr * 40 + g * 4]) = w0;
        *reinterpret_cast<u16x4*>(&P_lds[w][lr * 40 + 16 + g * 4]) = w1;
        // wave-internal DS ordering: same instruction stream, no barrier needed
        s16x8 bp8 = *reinterpret_cast<const s16x8*>(&P_lds[w][lr * 40 + g * 8]);
#pragma unroll
        for (int dt = 0; dt < 4; ++dt) {
            s16x8 av = *reinterpret_cast<const s16x8*>(Vt + (size_t)(dt * 16 + lr) * TB + k0 + g * 8);
            oacc[dt] = __builtin_amdgcn_mfma_f32_16x16x32_bf16(av, bp8, oacc[dt], 0, 0, 0);
        }
    }

    const float inv_l = 1.0f / l_i;
    // O^T[d = dt*16+g*4+r][q = lr] -> og[(b*T + q)*C + h*64 + d]
    unsigned short* orow = og + ((size_t)(b * TB + q_idx)) * CD + h * 64;
#pragma unroll
    for (int dt = 0; dt < 4; ++dt) {
        u16x4 ov = { f2bf(oacc[dt][0] * inv_l), f2bf(oacc[dt][1] * inv_l),
                     f2bf(oacc[dt][2] * inv_l), f2bf(oacc[dt][3] * inv_l) };
        *reinterpret_cast<u16x4*>(orow + dt * 16 + g * 4) = ov;
    }
}

extern "C" void kernel_launch(void* const* d_in, const int* in_sizes, int n_in,
                              void* d_out, int out_size, void* d_ws, size_t ws_size,
                              hipStream_t stream)
{
    const float* x  = (const float*)d_in[0];
    const float* wq = (const float*)d_in[1];
    const float* bq = (const float*)d_in[2];
    const float* wk = (const float*)d_in[3];
    const float* bk = (const float*)d_in[4];
    const float* wv = (const float*)d_in[5];
    const float* bv = (const float*)d_in[6];
    const float* wp = (const float*)d_in[7];
    const float* bp = (const float*)d_in[8];
    float* out = (float*)d_out;

    // workspace layout (ushort elems), peak 75.5 MB:
    // ob aliases xb — x_bf16 is dead after gemm<0>, attn_k writes ob afterwards
    // (same stream => ordered; same work every call => graph-replay safe)
    unsigned short* xb   = (unsigned short*)d_ws;      // 8388608 (x bf16 / attn out)
    unsigned short* wcat = xb + 8388608;               // 3145728 (wq|wk|wv)
    unsigned short* wpb  = wcat + 3145728;             // 1048576
    unsigned short* qb_  = wpb + 1048576;              // 8388608 (B,H,T,HD)
    unsigned short* kb_  = qb_ + 8388608;              // 8388608 (B,H,T,HD)
    unsigned short* vtb  = kb_ + 8388608;              // 8388608 (B,H,HD,T)
    unsigned short* ob   = xb;                         // alias

    cast_k<<<8192, 256, 0, stream>>>(x, xb, 2097152);
    cast_k<<<1024, 256, 0, stream>>>(wq, wcat, 262144);
    cast_k<<<1024, 256, 0, stream>>>(wk, wcat + 1048576, 262144);
    cast_k<<<1024, 256, 0, stream>>>(wv, wcat + 2097152, 262144);
    cast_k<<<1024, 256, 0, stream>>>(wp, wpb, 262144);

    gemm_bt<0><<<dim3(24, 64), 256, 0, stream>>>(xb, wcat, qb_, kb_, vtb,
                                                 bq, bk, bv, nullptr, nullptr);
    attn_k<<<dim3(32, 64), 256, 0, stream>>>(qb_, kb_, vtb, ob);
    gemm_bt<1><<<dim3(8, 64), 256, 0, stream>>>(ob, wpb, nullptr, nullptr, nullptr,
                                                nullptr, nullptr, nullptr, out, bp);
}

// Round 6
// 454.216 us; speedup vs baseline: 1.4746x; 1.4746x over previous
//
#include <hip/hip_runtime.h>
#include <stdint.h>
#include <math.h>

#define TB 2048
#define CD 1024

typedef short s16x8 __attribute__((ext_vector_type(8)));
typedef unsigned short u16x4 __attribute__((ext_vector_type(4)));
typedef float f32x4 __attribute__((ext_vector_type(4)));

#define QSCALE 0.02209708691207961f  /* 1/sqrt(2048): ref scales by 1/sqrt(T) */

__device__ __forceinline__ unsigned short f2bf(float f) {
    union { float f; uint32_t u; } v; v.f = f;
    return (unsigned short)((v.u + 0x7fffu + ((v.u >> 16) & 1u)) >> 16);
}

// ---------------- cast fp32 -> bf16 (vectorized x4) ----------------
__global__ void cast_k(const float* __restrict__ src, unsigned short* __restrict__ dst, int n4) {
    int i = blockIdx.x * blockDim.x + threadIdx.x;
    if (i < n4) {
        float4 v = reinterpret_cast<const float4*>(src)[i];
        u16x4 o = { f2bf(v.x), f2bf(v.y), f2bf(v.z), f2bf(v.w) };
        reinterpret_cast<u16x4*>(dst)[i] = o;
    }
}

// ---------------- GEMM C = A(M,K) * Bw(N,K)^T ----------------
// MODE 0: A = x_bf16 (8192x1024), Bw = [wq;wk;wv] (3072x1024)
//         writes q (pre-scaled by QSCALE), k (B,H,T,HD) bf16, v transposed
//         (B,H,HD,T) bf16, + bias
// MODE 1: A = attn_out (8192x1024), Bw = wp (1024x1024) -> fp32 out + bias
template<int MODE>
__launch_bounds__(256)
__global__ void gemm_bt(const unsigned short* __restrict__ A,
                        const unsigned short* __restrict__ Bw,
                        unsigned short* __restrict__ qo,
                        unsigned short* __restrict__ ko,
                        unsigned short* __restrict__ vto,
                        const float* __restrict__ b0,
                        const float* __restrict__ b1,
                        const float* __restrict__ b2,
                        float* __restrict__ fout,
                        const float* __restrict__ bp)
{
    __shared__ unsigned short As[128 * 40];
    __shared__ unsigned short Bs[128 * 40];
    const int tid = threadIdx.x;
    const int mbase = blockIdx.y * 128;
    const int nbase = blockIdx.x * 128;
    const int lane = tid & 63;
    const int w = tid >> 6;
    const int g = lane >> 4;
    const int lr = lane & 15;
    const int wm = (w >> 1) * 64;
    const int wn = (w & 1) * 64;
    const int row_l = tid >> 2;
    const int col8 = (tid & 3) * 8;

    f32x4 acc[4][4];
#pragma unroll
    for (int i = 0; i < 4; ++i)
#pragma unroll
        for (int j = 0; j < 4; ++j) acc[i][j] = (f32x4)0.0f;

    for (int k0 = 0; k0 < 1024; k0 += 32) {
        __syncthreads();
#pragma unroll
        for (int p = 0; p < 2; ++p) {
            const int r = row_l + p * 64;
            *reinterpret_cast<s16x8*>(&As[r * 40 + col8]) =
                *reinterpret_cast<const s16x8*>(A + (size_t)(mbase + r) * 1024 + k0 + col8);
            *reinterpret_cast<s16x8*>(&Bs[r * 40 + col8]) =
                *reinterpret_cast<const s16x8*>(Bw + (size_t)(nbase + r) * 1024 + k0 + col8);
        }
        __syncthreads();
        s16x8 af[4], bfv[4];
#pragma unroll
        for (int mi = 0; mi < 4; ++mi)
            af[mi] = *reinterpret_cast<const s16x8*>(&As[(wm + mi * 16 + lr) * 40 + g * 8]);
#pragma unroll
        for (int ni = 0; ni < 4; ++ni)
            bfv[ni] = *reinterpret_cast<const s16x8*>(&Bs[(wn + ni * 16 + lr) * 40 + g * 8]);
#pragma unroll
        for (int mi = 0; mi < 4; ++mi)
#pragma unroll
            for (int ni = 0; ni < 4; ++ni)
                acc[mi][ni] = __builtin_amdgcn_mfma_f32_16x16x32_bf16(af[mi], bfv[ni], acc[mi][ni], 0, 0, 0);
    }

#pragma unroll
    for (int mi = 0; mi < 4; ++mi) {
        const int mg = mbase + wm + mi * 16 + g * 4;
#pragma unroll
        for (int ni = 0; ni < 4; ++ni) {
            const int ng = nbase + wn + ni * 16 + lr;
            if constexpr (MODE == 0) {
                const int which = ng >> 10;
                const int nin = ng & 1023;
                const float bias = (which == 0) ? b0[nin] : (which == 1) ? b1[nin] : b2[nin];
                const int h = nin >> 6, d = nin & 63;
                const int b = mg >> 11, t = mg & 2047;
                if (which == 2) {
                    u16x4 pv = { f2bf(acc[mi][ni][0] + bias), f2bf(acc[mi][ni][1] + bias),
                                 f2bf(acc[mi][ni][2] + bias), f2bf(acc[mi][ni][3] + bias) };
                    *reinterpret_cast<u16x4*>(vto + ((size_t)((b * 16 + h) * 64 + d)) * 2048 + t) = pv;
                } else if (which == 0) {
#pragma unroll
                    for (int r = 0; r < 4; ++r)
                        qo[((size_t)(b * 16 + h) * 2048 + (t + r)) * 64 + d] =
                            f2bf((acc[mi][ni][r] + bias) * QSCALE);
                } else {
#pragma unroll
                    for (int r = 0; r < 4; ++r)
                        ko[((size_t)(b * 16 + h) * 2048 + (t + r)) * 64 + d] = f2bf(acc[mi][ni][r] + bias);
                }
            } else {
                const float bias = bp[ng];
#pragma unroll
                for (int r = 0; r < 4; ++r)
                    fout[(size_t)(mg + r) * 1024 + ng] = acc[mi][ni][r] + bias;
            }
        }
    }
}

// ---------------- flash attention, 32q/wave, 64-key tiles ----------------
// grid (16 qsupers, 64 bh); 256 threads = 4 independent waves (no barriers).
// Wave w handles q-rows [qs*128 + w*32, +32). S^T = K*Q^T per 16-key subtile
// (lane owns q-col lr); softmax reduce = local + 2 shfl_xor. P through a
// per-wave XOR-swizzled LDS buffer; PV as O^T = V^T * P^T (V pre-transposed).
// K double-buffered in regs (prefetch t+1 before QK of t); V issued at tile
// start (consumed post-softmax). K/V are L2-resident: no LDS staging.
__launch_bounds__(256, 2)
__global__ void attn_k(const unsigned short* __restrict__ qg,
                       const unsigned short* __restrict__ kg,
                       const unsigned short* __restrict__ vtg,
                       unsigned short* __restrict__ og)
{
    __shared__ unsigned short P_lds[4][32 * 64];  // per-wave 32q x 64key, swizzled
    const int qs = blockIdx.x;
    const int bh = blockIdx.y;
    const int b = bh >> 4;
    const int h = bh & 15;
    const int tid = threadIdx.x;
    const int w = tid >> 6;
    const int lane = tid & 63;
    const int g = lane >> 4;
    const int lr = lane & 15;
    const int qw = qs * 128 + w * 32;

    const unsigned short* Qp = qg + (size_t)bh * TB * 64;
    const unsigned short* Kp = kg + (size_t)bh * TB * 64;
    const unsigned short* Vt = vtg + (size_t)bh * 64 * TB;

    // Q fragments (B-operand), q pre-scaled in GEMM epilogue
    s16x8 bq[2][2];
#pragma unroll
    for (int qf = 0; qf < 2; ++qf) {
        const unsigned short* qp = Qp + (size_t)(qw + qf * 16 + lr) * 64 + g * 8;
        bq[qf][0] = *reinterpret_cast<const s16x8*>(qp);
        bq[qf][1] = *reinterpret_cast<const s16x8*>(qp + 32);
    }

    f32x4 oacc[4][2];
#pragma unroll
    for (int dt = 0; dt < 4; ++dt)
#pragma unroll
        for (int qf = 0; qf < 2; ++qf) oacc[dt][qf] = (f32x4)0.0f;
    float mi[2] = { -INFINITY, -INFINITY };
    float li[2] = { 0.0f, 0.0f };

    const int nt = (qw >> 6) + 1;
    const unsigned short* kfb = Kp + (size_t)lr * 64 + g * 8;   // + key*64
    const unsigned short* vfb = Vt + (size_t)lr * TB + g * 8;   // + dt*16*TB + key

    s16x8 kA[8], kB[8];
#pragma unroll
    for (int sub = 0; sub < 4; ++sub) {
        kA[sub * 2]     = *reinterpret_cast<const s16x8*>(kfb + sub * 1024);
        kA[sub * 2 + 1] = *reinterpret_cast<const s16x8*>(kfb + sub * 1024 + 32);
    }

    unsigned short* Pw = P_lds[w];

    auto PROC = [&](s16x8 (&kc)[8], s16x8 (&kn)[8], int t) {
        const int k0 = t * 64;
        // V for this tile (needed only after softmax: latency hidden)
        s16x8 vf[8];
        const unsigned short* vp = vfb + k0;
#pragma unroll
        for (int dt = 0; dt < 4; ++dt)
#pragma unroll
            for (int ks = 0; ks < 2; ++ks)
                vf[dt * 2 + ks] = *reinterpret_cast<const s16x8*>(vp + (size_t)dt * 16 * TB + ks * 32);
        // prefetch next K tile (consumed next iteration)
        if (t + 1 < nt) {
            const unsigned short* kp = kfb + (size_t)(k0 + 64) * 64;
#pragma unroll
            for (int sub = 0; sub < 4; ++sub) {
                kn[sub * 2]     = *reinterpret_cast<const s16x8*>(kp + sub * 1024);
                kn[sub * 2 + 1] = *reinterpret_cast<const s16x8*>(kp + sub * 1024 + 32);
            }
        }
        // S^T = K * Q^T : 4 key-subtiles x 2 q-frags
        f32x4 st[4][2];
#pragma unroll
        for (int sub = 0; sub < 4; ++sub)
#pragma unroll
            for (int qf = 0; qf < 2; ++qf) {
                f32x4 z = (f32x4)0.0f;
                z = __builtin_amdgcn_mfma_f32_16x16x32_bf16(kc[sub * 2], bq[qf][0], z, 0, 0, 0);
                st[sub][qf] = __builtin_amdgcn_mfma_f32_16x16x32_bf16(kc[sub * 2 + 1], bq[qf][1], z, 0, 0, 0);
            }
        if (t == nt - 1) {  // causal mask, boundary tile only (wave-uniform branch)
#pragma unroll
            for (int sub = 0; sub < 4; ++sub)
#pragma unroll
                for (int qf = 0; qf < 2; ++qf)
#pragma unroll
                    for (int r = 0; r < 4; ++r) {
                        const int key = k0 + sub * 16 + g * 4 + r;
                        const int q = qw + qf * 16 + lr;
                        if (key > q) st[sub][qf][r] = -INFINITY;
                    }
        }
        // online softmax per q-frag (lane owns q-col lr; reduce over g via shfl)
        float alpha[2];
#pragma unroll
        for (int qf = 0; qf < 2; ++qf) {
            float mloc = st[0][qf][0];
#pragma unroll
            for (int sub = 0; sub < 4; ++sub)
#pragma unroll
                for (int r = 0; r < 4; ++r) mloc = fmaxf(mloc, st[sub][qf][r]);
            mloc = fmaxf(mloc, __shfl_xor(mloc, 16));
            mloc = fmaxf(mloc, __shfl_xor(mloc, 32));
            const float mn = fmaxf(mi[qf], mloc);
            alpha[qf] = __expf(mi[qf] - mn);
            mi[qf] = mn;
            float ps = 0.0f;
#pragma unroll
            for (int sub = 0; sub < 4; ++sub)
#pragma unroll
                for (int r = 0; r < 4; ++r) {
                    const float p = __expf(st[sub][qf][r] - mn);
                    st[sub][qf][r] = p;
                    ps += p;
                }
            ps += __shfl_xor(ps, 16);
            ps += __shfl_xor(ps, 32);
            li[qf] = li[qf] * alpha[qf] + ps;
        }
#pragma unroll
        for (int dt = 0; dt < 4; ++dt)
#pragma unroll
            for (int qf = 0; qf < 2; ++qf) oacc[dt][qf] *= alpha[qf];
        // P -> LDS (XOR granule swizzle: balanced banks on write & read)
#pragma unroll
        for (int sub = 0; sub < 4; ++sub)
#pragma unroll
            for (int qf = 0; qf < 2; ++qf) {
                u16x4 pk = { f2bf(st[sub][qf][0]), f2bf(st[sub][qf][1]),
                             f2bf(st[sub][qf][2]), f2bf(st[sub][qf][3]) };
                const int row = qf * 16 + lr;
                const int bo = sub * 32 + g * 8;
                const int phys = ((bo >> 4) ^ (row & 7)) * 16 + (bo & 15);
                *reinterpret_cast<u16x4*>(reinterpret_cast<char*>(Pw + row * 64) + phys) = pk;
            }
        // PV: O^T += V^T * P^T (wave-internal DS pipe is in-order: no barrier)
#pragma unroll
        for (int qf = 0; qf < 2; ++qf)
#pragma unroll
            for (int ks = 0; ks < 2; ++ks) {
                const int row = qf * 16 + lr;
                const int gran = (ks * 4 + g) ^ (row & 7);
                s16x8 pb = *reinterpret_cast<const s16x8*>(
                    reinterpret_cast<const char*>(Pw + row * 64) + gran * 16);
#pragma unroll
                for (int dt = 0; dt < 4; ++dt)
                    oacc[dt][qf] = __builtin_amdgcn_mfma_f32_16x16x32_bf16(vf[dt * 2 + ks], pb, oacc[dt][qf], 0, 0, 0);
            }
    };

    int t = 0;
    for (;;) {                 // 2-deep unroll: kA/kB statically indexed (rule #20)
        PROC(kA, kB, t);
        if (++t >= nt) break;
        PROC(kB, kA, t);
        if (++t >= nt) break;
    }

#pragma unroll
    for (int qf = 0; qf < 2; ++qf) {
        const float inv_l = 1.0f / li[qf];
        unsigned short* orow = og + ((size_t)(b * TB + qw + qf * 16 + lr)) * CD + h * 64;
#pragma unroll
        for (int dt = 0; dt < 4; ++dt) {
            u16x4 ov = { f2bf(oacc[dt][qf][0] * inv_l), f2bf(oacc[dt][qf][1] * inv_l),
                         f2bf(oacc[dt][qf][2] * inv_l), f2bf(oacc[dt][qf][3] * inv_l) };
            *reinterpret_cast<u16x4*>(orow + dt * 16 + g * 4) = ov;
        }
    }
}

extern "C" void kernel_launch(void* const* d_in, const int* in_sizes, int n_in,
                              void* d_out, int out_size, void* d_ws, size_t ws_size,
                              hipStream_t stream)
{
    const float* x  = (const float*)d_in[0];
    const float* wq = (const float*)d_in[1];
    const float* bq = (const float*)d_in[2];
    const float* wk = (const float*)d_in[3];
    const float* bk = (const float*)d_in[4];
    const float* wv = (const float*)d_in[5];
    const float* bv = (const float*)d_in[6];
    const float* wp = (const float*)d_in[7];
    const float* bp = (const float*)d_in[8];
    float* out = (float*)d_out;

    // workspace (ushort elems), peak 75.5 MB; ob aliases xb (x dead after gemm<0>)
    unsigned short* xb   = (unsigned short*)d_ws;      // 8388608 (x bf16 / attn out)
    unsigned short* wcat = xb + 8388608;               // 3145728 (wq|wk|wv)
    unsigned short* wpb  = wcat + 3145728;             // 1048576
    unsigned short* qb_  = wpb + 1048576;              // 8388608 (B,H,T,HD) pre-scaled
    unsigned short* kb_  = qb_ + 8388608;              // 8388608 (B,H,T,HD)
    unsigned short* vtb  = kb_ + 8388608;              // 8388608 (B,H,HD,T)
    unsigned short* ob   = xb;                         // alias

    cast_k<<<8192, 256, 0, stream>>>(x, xb, 2097152);
    cast_k<<<1024, 256, 0, stream>>>(wq, wcat, 262144);
    cast_k<<<1024, 256, 0, stream>>>(wk, wcat + 1048576, 262144);
    cast_k<<<1024, 256, 0, stream>>>(wv, wcat + 2097152, 262144);
    cast_k<<<1024, 256, 0, stream>>>(wp, wpb, 262144);

    gemm_bt<0><<<dim3(24, 64), 256, 0, stream>>>(xb, wcat, qb_, kb_, vtb,
                                                 bq, bk, bv, nullptr, nullptr);
    attn_k<<<dim3(16, 64), 256, 0, stream>>>(qb_, kb_, vtb, ob);
    gemm_bt<1><<<dim3(8, 64), 256, 0, stream>>>(ob, wpb, nullptr, nullptr, nullptr,
                                                nullptr, nullptr, nullptr, out, bp);
}

// Round 8
// 310.779 us; speedup vs baseline: 2.1551x; 1.4615x over previous
//
#include <hip/hip_runtime.h>
#include <stdint.h>
#include <math.h>

#define TB 2048
#define CD 1024

typedef short s16x8 __attribute__((ext_vector_type(8)));
typedef unsigned short u16x4 __attribute__((ext_vector_type(4)));
typedef float f32x4 __attribute__((ext_vector_type(4)));

#define QSCALE 0.02209708691207961f  /* 1/sqrt(2048): ref scales by 1/sqrt(T) */

__device__ __forceinline__ unsigned short f2bf(float f) {
    union { float f; uint32_t u; } v; v.f = f;
    return (unsigned short)((v.u + 0x7fffu + ((v.u >> 16) & 1u)) >> 16);
}

// async global->LDS, 16B per lane; dest = wave-uniform base + lane*16 (HW rule)
__device__ __forceinline__ void gl_lds16(const void* g, void* l) {
    typedef const __attribute__((address_space(1))) unsigned int gu32;
    typedef __attribute__((address_space(3))) unsigned int lu32;
    __builtin_amdgcn_global_load_lds((gu32*)g, (lu32*)l, 16, 0, 0);
}

// ---------------- cast fp32 -> bf16 (vectorized x4) ----------------
__global__ void cast_k(const float* __restrict__ src, unsigned short* __restrict__ dst, int n4) {
    int i = blockIdx.x * blockDim.x + threadIdx.x;
    if (i < n4) {
        float4 v = reinterpret_cast<const float4*>(src)[i];
        u16x4 o = { f2bf(v.x), f2bf(v.y), f2bf(v.z), f2bf(v.w) };
        reinterpret_cast<u16x4*>(dst)[i] = o;
    }
}

// ---------------- GEMM C = A(M,K) * Bw(N,K)^T  (unchanged this round) ----------------
template<int MODE>
__launch_bounds__(256)
__global__ void gemm_bt(const unsigned short* __restrict__ A,
                        const unsigned short* __restrict__ Bw,
                        unsigned short* __restrict__ qo,
                        unsigned short* __restrict__ ko,
                        unsigned short* __restrict__ vto,
                        const float* __restrict__ b0,
                        const float* __restrict__ b1,
                        const float* __restrict__ b2,
                        float* __restrict__ fout,
                        const float* __restrict__ bp)
{
    __shared__ unsigned short As[128 * 40];
    __shared__ unsigned short Bs[128 * 40];
    const int tid = threadIdx.x;
    const int mbase = blockIdx.y * 128;
    const int nbase = blockIdx.x * 128;
    const int lane = tid & 63;
    const int w = tid >> 6;
    const int g = lane >> 4;
    const int lr = lane & 15;
    const int wm = (w >> 1) * 64;
    const int wn = (w & 1) * 64;
    const int row_l = tid >> 2;
    const int col8 = (tid & 3) * 8;

    f32x4 acc[4][4];
#pragma unroll
    for (int i = 0; i < 4; ++i)
#pragma unroll
        for (int j = 0; j < 4; ++j) acc[i][j] = (f32x4)0.0f;

    for (int k0 = 0; k0 < 1024; k0 += 32) {
        __syncthreads();
#pragma unroll
        for (int p = 0; p < 2; ++p) {
            const int r = row_l + p * 64;
            *reinterpret_cast<s16x8*>(&As[r * 40 + col8]) =
                *reinterpret_cast<const s16x8*>(A + (size_t)(mbase + r) * 1024 + k0 + col8);
            *reinterpret_cast<s16x8*>(&Bs[r * 40 + col8]) =
                *reinterpret_cast<const s16x8*>(Bw + (size_t)(nbase + r) * 1024 + k0 + col8);
        }
        __syncthreads();
        s16x8 af[4], bfv[4];
#pragma unroll
        for (int mi = 0; mi < 4; ++mi)
            af[mi] = *reinterpret_cast<const s16x8*>(&As[(wm + mi * 16 + lr) * 40 + g * 8]);
#pragma unroll
        for (int ni = 0; ni < 4; ++ni)
            bfv[ni] = *reinterpret_cast<const s16x8*>(&Bs[(wn + ni * 16 + lr) * 40 + g * 8]);
#pragma unroll
        for (int mi = 0; mi < 4; ++mi)
#pragma unroll
            for (int ni = 0; ni < 4; ++ni)
                acc[mi][ni] = __builtin_amdgcn_mfma_f32_16x16x32_bf16(af[mi], bfv[ni], acc[mi][ni], 0, 0, 0);
    }

#pragma unroll
    for (int mi = 0; mi < 4; ++mi) {
        const int mg = mbase + wm + mi * 16 + g * 4;
#pragma unroll
        for (int ni = 0; ni < 4; ++ni) {
            const int ng = nbase + wn + ni * 16 + lr;
            if constexpr (MODE == 0) {
                const int which = ng >> 10;
                const int nin = ng & 1023;
                const float bias = (which == 0) ? b0[nin] : (which == 1) ? b1[nin] : b2[nin];
                const int h = nin >> 6, d = nin & 63;
                const int b = mg >> 11, t = mg & 2047;
                if (which == 2) {
                    u16x4 pv = { f2bf(acc[mi][ni][0] + bias), f2bf(acc[mi][ni][1] + bias),
                                 f2bf(acc[mi][ni][2] + bias), f2bf(acc[mi][ni][3] + bias) };
                    *reinterpret_cast<u16x4*>(vto + ((size_t)((b * 16 + h) * 64 + d)) * 2048 + t) = pv;
                } else if (which == 0) {
#pragma unroll
                    for (int r = 0; r < 4; ++r)
                        qo[((size_t)(b * 16 + h) * 2048 + (t + r)) * 64 + d] =
                            f2bf((acc[mi][ni][r] + bias) * QSCALE);
                } else {
#pragma unroll
                    for (int r = 0; r < 4; ++r)
                        ko[((size_t)(b * 16 + h) * 2048 + (t + r)) * 64 + d] = f2bf(acc[mi][ni][r] + bias);
                }
            } else {
                const float bias = bp[ng];
#pragma unroll
                for (int r = 0; r < 4; ++r)
                    fout[(size_t)(mg + r) * 1024 + ng] = acc[mi][ni][r] + bias;
            }
        }
    }
}

// ---------------- flash attention v3 ----------------
// grid (8, 64). Block = 4 waves; runs TWO q-supers (p and 15-p) sequentially
// -> 34 K-tiles per block, uniform (no triangular tail). K/V tiles (64 keys)
// staged once per block into double-buffered LDS via global_load_lds(16B),
// raw s_barrier + counted vmcnt(4) so next-tile loads stay in flight (T3/T4).
// XOR chunk swizzle (phys = chunk ^ (row&7)) applied via inverse-permuted
// GLOBAL source + swizzled ds_read (both-sides rule). Per-wave: 32 q-rows,
// S^T = K*Q^T (lane owns q-col), softmax local+2 shfl, P via per-wave
// swizzled LDS roundtrip, O^T = V^T * P^T.
__launch_bounds__(256, 2)
__global__ void attn_k(const unsigned short* __restrict__ qg,
                       const unsigned short* __restrict__ kg,
                       const unsigned short* __restrict__ vtg,
                       unsigned short* __restrict__ og)
{
    __shared__ unsigned short Kt[2][64 * 64];   // [buf][key][d], chunks XOR-swizzled
    __shared__ unsigned short Vs[2][64 * 64];   // [buf][d][key], chunks XOR-swizzled
    __shared__ unsigned short P_lds[4][32 * 64];

    const int pr = blockIdx.x;        // 0..7
    const int bh = blockIdx.y;
    const int b = bh >> 4, h = bh & 15;
    const int tid = threadIdx.x;
    const int w = tid >> 6;
    const int lane = tid & 63;
    const int g = lane >> 4;
    const int lr = lane & 15;

    const unsigned short* Qp = qg + (size_t)bh * TB * 64;
    const unsigned short* Kp = kg + (size_t)bh * TB * 64;
    const unsigned short* Vt = vtg + (size_t)bh * 64 * TB;
    unsigned short* Pw = P_lds[w];

    // staging decomposition: wave w stages segments {2w, 2w+1} of each tile.
    // segment = 8 rows x 128B; lane -> (row srow, 16B chunk schk); source chunk
    // pre-XORed so LDS[row][c] = G[row][c ^ (row&7)]  (row&7 == srow).
    const int srow = lane >> 3;
    const int schk = lane & 7;
    const int gchk = schk ^ srow;
    const int seg0 = w * 2, seg1 = w * 2 + 1;
    const int swz = (lr & 7);          // read-side XOR

#pragma unroll 1
    for (int half = 0; half < 2; ++half) {
        const int sup = half == 0 ? pr : 15 - pr;
        const int qw = sup * 128 + w * 32;
        const int ntw = (qw >> 6) + 1;       // this wave's causal tile count
        const int NT = sup * 2 + 2;          // block-max tile count (uniform)

        // Q fragments (pre-scaled by QSCALE in GEMM epilogue)
        s16x8 bq0[2], bq1[2];
#pragma unroll
        for (int qf = 0; qf < 2; ++qf) {
            const unsigned short* qp = Qp + (size_t)(qw + qf * 16 + lr) * 64 + g * 8;
            bq0[qf] = *reinterpret_cast<const s16x8*>(qp);
            bq1[qf] = *reinterpret_cast<const s16x8*>(qp + 32);
        }

        f32x4 oacc[4][2];
#pragma unroll
        for (int dt = 0; dt < 4; ++dt)
#pragma unroll
            for (int qf = 0; qf < 2; ++qf) oacc[dt][qf] = (f32x4)0.0f;
        float mi_[2] = { -INFINITY, -INFINITY };
        float li_[2] = { 0.0f, 0.0f };

        // ---- prologue: drain LDS readers (prev half), stage tile 0 ----
        asm volatile("s_waitcnt lgkmcnt(0)" ::: "memory");
        __builtin_amdgcn_s_barrier();
        {
            gl_lds16(Kp + (size_t)(seg0 * 8 + srow) * 64 + gchk * 8, &Kt[0][seg0 * 512]);
            gl_lds16(Kp + (size_t)(seg1 * 8 + srow) * 64 + gchk * 8, &Kt[0][seg1 * 512]);
            gl_lds16(Vt + (size_t)(seg0 * 8 + srow) * TB + gchk * 8, &Vs[0][seg0 * 512]);
            gl_lds16(Vt + (size_t)(seg1 * 8 + srow) * TB + gchk * 8, &Vs[0][seg1 * 512]);
        }
        asm volatile("s_waitcnt vmcnt(0)" ::: "memory");
        __builtin_amdgcn_s_barrier();
        asm volatile("" ::: "memory");
        __builtin_amdgcn_sched_barrier(0);

        int cur = 0;
#pragma unroll 1
        for (int t = 0; t < NT; ++t) {
            const int other = cur ^ 1;
            if (t > 0) {
                // all waves done reading 'other' (tile t-1) before we overwrite it
                asm volatile("s_waitcnt lgkmcnt(0)" ::: "memory");
                __builtin_amdgcn_s_barrier();
            }
            if (t + 1 < NT) {
                const int k0n = (t + 1) * 64;
                gl_lds16(Kp + (size_t)(k0n + seg0 * 8 + srow) * 64 + gchk * 8, &Kt[other][seg0 * 512]);
                gl_lds16(Kp + (size_t)(k0n + seg1 * 8 + srow) * 64 + gchk * 8, &Kt[other][seg1 * 512]);
                gl_lds16(Vt + (size_t)(seg0 * 8 + srow) * TB + k0n + gchk * 8, &Vs[other][seg0 * 512]);
                gl_lds16(Vt + (size_t)(seg1 * 8 + srow) * TB + k0n + gchk * 8, &Vs[other][seg1 * 512]);
                asm volatile("s_waitcnt vmcnt(4)" ::: "memory");   // tile-t loads landed; t+1 in flight
            } else {
                asm volatile("s_waitcnt vmcnt(0)" ::: "memory");
            }
            __builtin_amdgcn_s_barrier();       // everyone's tile-t data in LDS
            asm volatile("" ::: "memory");
            __builtin_amdgcn_sched_barrier(0);

            if (t < ntw) {
                const unsigned short* Kc = Kt[cur];
                const unsigned short* Vc = Vs[cur];
                // ---- S^T = K * Q^T ----
                f32x4 st[4][2];
#pragma unroll
                for (int sub = 0; sub < 4; ++sub) {
                    const unsigned short* krow = Kc + (sub * 16 + lr) * 64;
                    s16x8 ak0 = *reinterpret_cast<const s16x8*>(krow + ((g ^ swz) * 8));
                    s16x8 ak1 = *reinterpret_cast<const s16x8*>(krow + (((g + 4) ^ swz) * 8));
#pragma unroll
                    for (int qf = 0; qf < 2; ++qf) {
                        f32x4 z = (f32x4)0.0f;
                        z = __builtin_amdgcn_mfma_f32_16x16x32_bf16(ak0, bq0[qf], z, 0, 0, 0);
                        st[sub][qf] = __builtin_amdgcn_mfma_f32_16x16x32_bf16(ak1, bq1[qf], z, 0, 0, 0);
                    }
                }
                if (t == ntw - 1) {  // causal boundary tile (wave-uniform branch)
                    const int k0 = t * 64;
#pragma unroll
                    for (int sub = 0; sub < 4; ++sub)
#pragma unroll
                        for (int qf = 0; qf < 2; ++qf)
#pragma unroll
                            for (int r = 0; r < 4; ++r) {
                                const int key = k0 + sub * 16 + g * 4 + r;
                                const int q = qw + qf * 16 + lr;
                                if (key > q) st[sub][qf][r] = -INFINITY;
                            }
                }
                // ---- online softmax (lane owns q-col lr; reduce over g) ----
                float alpha[2];
#pragma unroll
                for (int qf = 0; qf < 2; ++qf) {
                    float mloc = st[0][qf][0];
#pragma unroll
                    for (int sub = 0; sub < 4; ++sub)
#pragma unroll
                        for (int r = 0; r < 4; ++r) mloc = fmaxf(mloc, st[sub][qf][r]);
                    mloc = fmaxf(mloc, __shfl_xor(mloc, 16));
                    mloc = fmaxf(mloc, __shfl_xor(mloc, 32));
                    const float mn = fmaxf(mi_[qf], mloc);
                    alpha[qf] = __expf(mi_[qf] - mn);
                    mi_[qf] = mn;
                    float ps = 0.0f;
#pragma unroll
                    for (int sub = 0; sub < 4; ++sub)
#pragma unroll
                        for (int r = 0; r < 4; ++r) {
                            const float p = __expf(st[sub][qf][r] - mn);
                            st[sub][qf][r] = p;
                            ps += p;
                        }
                    ps += __shfl_xor(ps, 16);
                    ps += __shfl_xor(ps, 32);
                    li_[qf] = li_[qf] * alpha[qf] + ps;
                }
#pragma unroll
                for (int dt = 0; dt < 4; ++dt)
#pragma unroll
                    for (int qf = 0; qf < 2; ++qf) oacc[dt][qf] *= alpha[qf];
                // ---- P -> per-wave LDS (XOR granule swizzle) ----
#pragma unroll
                for (int sub = 0; sub < 4; ++sub)
#pragma unroll
                    for (int qf = 0; qf < 2; ++qf) {
                        u16x4 pk = { f2bf(st[sub][qf][0]), f2bf(st[sub][qf][1]),
                                     f2bf(st[sub][qf][2]), f2bf(st[sub][qf][3]) };
                        const int row = qf * 16 + lr;
                        const int bo = sub * 32 + g * 8;
                        const int phys = ((bo >> 4) ^ (row & 7)) * 16 + (bo & 15);
                        *reinterpret_cast<u16x4*>(reinterpret_cast<char*>(Pw + row * 64) + phys) = pk;
                    }
                // ---- PV: O^T += V^T * P^T ----
                s16x8 vf[8];
#pragma unroll
                for (int dt = 0; dt < 4; ++dt)
#pragma unroll
                    for (int ks = 0; ks < 2; ++ks)
                        vf[dt * 2 + ks] = *reinterpret_cast<const s16x8*>(
                            Vc + (dt * 16 + lr) * 64 + (((ks * 4 + g) ^ swz) * 8));
#pragma unroll
                for (int qf = 0; qf < 2; ++qf)
#pragma unroll
                    for (int ks = 0; ks < 2; ++ks) {
                        const int row = qf * 16 + lr;
                        const int gran = (ks * 4 + g) ^ (row & 7);
                        s16x8 pb = *reinterpret_cast<const s16x8*>(
                            reinterpret_cast<const char*>(Pw + row * 64) + gran * 16);
#pragma unroll
                        for (int dt = 0; dt < 4; ++dt)
                            oacc[dt][qf] = __builtin_amdgcn_mfma_f32_16x16x32_bf16(vf[dt * 2 + ks], pb, oacc[dt][qf], 0, 0, 0);
                    }
            }
            cur = other;
        }

        // ---- epilogue: O^T[d][q] -> og[(b*T+q)*C + h*64 + d] ----
#pragma unroll
        for (int qf = 0; qf < 2; ++qf) {
            const float inv_l = 1.0f / li_[qf];
            unsigned short* orow = og + ((size_t)(b * TB + qw + qf * 16 + lr)) * CD + h * 64;
#pragma unroll
            for (int dt = 0; dt < 4; ++dt) {
                u16x4 ov = { f2bf(oacc[dt][qf][0] * inv_l), f2bf(oacc[dt][qf][1] * inv_l),
                             f2bf(oacc[dt][qf][2] * inv_l), f2bf(oacc[dt][qf][3] * inv_l) };
                *reinterpret_cast<u16x4*>(orow + dt * 16 + g * 4) = ov;
            }
        }
    }
}

extern "C" void kernel_launch(void* const* d_in, const int* in_sizes, int n_in,
                              void* d_out, int out_size, void* d_ws, size_t ws_size,
                              hipStream_t stream)
{
    const float* x  = (const float*)d_in[0];
    const float* wq = (const float*)d_in[1];
    const float* bq = (const float*)d_in[2];
    const float* wk = (const float*)d_in[3];
    const float* bk = (const float*)d_in[4];
    const float* wv = (const float*)d_in[5];
    const float* bv = (const float*)d_in[6];
    const float* wp = (const float*)d_in[7];
    const float* bp = (const float*)d_in[8];
    float* out = (float*)d_out;

    // workspace (ushort elems), peak 75.5 MB; ob aliases xb (x dead after gemm<0>)
    unsigned short* xb   = (unsigned short*)d_ws;      // 8388608 (x bf16 / attn out)
    unsigned short* wcat = xb + 8388608;               // 3145728 (wq|wk|wv)
    unsigned short* wpb  = wcat + 3145728;             // 1048576
    unsigned short* qb_  = wpb + 1048576;              // 8388608 (B,H,T,HD) pre-scaled
    unsigned short* kb_  = qb_ + 8388608;              // 8388608 (B,H,T,HD)
    unsigned short* vtb  = kb_ + 8388608;              // 8388608 (B,H,HD,T)
    unsigned short* ob   = xb;                         // alias

    cast_k<<<8192, 256, 0, stream>>>(x, xb, 2097152);
    cast_k<<<1024, 256, 0, stream>>>(wq, wcat, 262144);
    cast_k<<<1024, 256, 0, stream>>>(wk, wcat + 1048576, 262144);
    cast_k<<<1024, 256, 0, stream>>>(wv, wcat + 2097152, 262144);
    cast_k<<<1024, 256, 0, stream>>>(wp, wpb, 262144);

    gemm_bt<0><<<dim3(24, 64), 256, 0, stream>>>(xb, wcat, qb_, kb_, vtb,
                                                 bq, bk, bv, nullptr, nullptr);
    attn_k<<<dim3(8, 64), 256, 0, stream>>>(qb_, kb_, vtb, ob);
    gemm_bt<1><<<dim3(8, 64), 256, 0, stream>>>(ob, wpb, nullptr, nullptr, nullptr,
                                                nullptr, nullptr, nullptr, out, bp);
}

// Round 9
// 300.224 us; speedup vs baseline: 2.2309x; 1.0352x over previous
//
#include <hip/hip_runtime.h>
#include <stdint.h>
#include <math.h>

#define TB 2048
#define CD 1024

typedef short s16x8 __attribute__((ext_vector_type(8)));
typedef unsigned short u16x4 __attribute__((ext_vector_type(4)));
typedef float f32x4 __attribute__((ext_vector_type(4)));

#define QSCALE 0.02209708691207961f  /* 1/sqrt(2048): ref scales by 1/sqrt(T) */

__device__ __forceinline__ unsigned short f2bf(float f) {
    union { float f; uint32_t u; } v; v.f = f;
    return (unsigned short)((v.u + 0x7fffu + ((v.u >> 16) & 1u)) >> 16);
}

// async global->LDS, 16B per lane; dest = wave-uniform base + lane*16 (HW rule)
__device__ __forceinline__ void gl_lds16(const void* g, void* l) {
    typedef const __attribute__((address_space(1))) unsigned int gu32;
    typedef __attribute__((address_space(3))) unsigned int lu32;
    __builtin_amdgcn_global_load_lds((gu32*)g, (lu32*)l, 16, 0, 0);
}

// ---------------- cast fp32 -> bf16 (vectorized x4) ----------------
__global__ void cast_k(const float* __restrict__ src, unsigned short* __restrict__ dst, int n4) {
    int i = blockIdx.x * blockDim.x + threadIdx.x;
    if (i < n4) {
        float4 v = reinterpret_cast<const float4*>(src)[i];
        u16x4 o = { f2bf(v.x), f2bf(v.y), f2bf(v.z), f2bf(v.w) };
        reinterpret_cast<u16x4*>(dst)[i] = o;
    }
}

// ---------------- GEMM C = A(M,K) * Bw(N,K)^T ----------------
// m97 structure: 128x128 tile, BK=32, linear LDS [128][32], staged via
// global_load_lds(16B), 2-barrier K-loop. 4 waves, 64x64 out each.
// MODE 0: A = x_bf16 (8192x1024), Bw = [wq;wk;wv] (3072x1024)
//         writes q (pre-scaled by QSCALE), k (B,H,T,HD) bf16, v transposed
//         (B,H,HD,T) bf16, + bias
// MODE 1: A = attn_out (8192x1024), Bw = wp (1024x1024) -> fp32 out + bias
template<int MODE>
__launch_bounds__(256)
__global__ void gemm_bt(const unsigned short* __restrict__ A,
                        const unsigned short* __restrict__ Bw,
                        unsigned short* __restrict__ qo,
                        unsigned short* __restrict__ ko,
                        unsigned short* __restrict__ vto,
                        const float* __restrict__ b0,
                        const float* __restrict__ b1,
                        const float* __restrict__ b2,
                        float* __restrict__ fout,
                        const float* __restrict__ bp)
{
    __shared__ unsigned short As[128 * 32];   // linear: row*32 + col (gl_lds dest)
    __shared__ unsigned short Bs[128 * 32];
    const int tid = threadIdx.x;
    const int mbase = blockIdx.y * 128;
    const int nbase = blockIdx.x * 128;
    const int lane = tid & 63;
    const int w = tid >> 6;
    const int g = lane >> 4;
    const int lr = lane & 15;
    const int wm = (w >> 1) * 64;
    const int wn = (w & 1) * 64;
    // staging: wave w, instr i covers rows [i*64 + w*16, +16); lane -> row l>>2, chunk l&3
    const int srow = lane >> 2;          // 0..15
    const int scol = (lane & 3) * 8;     // ushort col: 0,8,16,24

    f32x4 acc[4][4];
#pragma unroll
    for (int i = 0; i < 4; ++i)
#pragma unroll
        for (int j = 0; j < 4; ++j) acc[i][j] = (f32x4)0.0f;

    const size_t arow0 = (size_t)(mbase + w * 16 + srow);
    const size_t arow1 = (size_t)(mbase + 64 + w * 16 + srow);
    const size_t brow0 = (size_t)(nbase + w * 16 + srow);
    const size_t brow1 = (size_t)(nbase + 64 + w * 16 + srow);
    unsigned short* asd0 = As + (w * 16) * 32;
    unsigned short* asd1 = As + (64 + w * 16) * 32;
    unsigned short* bsd0 = Bs + (w * 16) * 32;
    unsigned short* bsd1 = Bs + (64 + w * 16) * 32;

    for (int k0 = 0; k0 < 1024; k0 += 32) {
        __syncthreads();   // all LDS readers of previous tile done
        gl_lds16(A  + arow0 * 1024 + k0 + scol, asd0);
        gl_lds16(A  + arow1 * 1024 + k0 + scol, asd1);
        gl_lds16(Bw + brow0 * 1024 + k0 + scol, bsd0);
        gl_lds16(Bw + brow1 * 1024 + k0 + scol, bsd1);
        __syncthreads();   // compiler drains vmcnt(0) before barrier: tile staged
        s16x8 af[4], bfv[4];
#pragma unroll
        for (int mi = 0; mi < 4; ++mi)
            af[mi] = *reinterpret_cast<const s16x8*>(&As[(wm + mi * 16 + lr) * 32 + g * 8]);
#pragma unroll
        for (int ni = 0; ni < 4; ++ni)
            bfv[ni] = *reinterpret_cast<const s16x8*>(&Bs[(wn + ni * 16 + lr) * 32 + g * 8]);
#pragma unroll
        for (int mi = 0; mi < 4; ++mi)
#pragma unroll
            for (int ni = 0; ni < 4; ++ni)
                acc[mi][ni] = __builtin_amdgcn_mfma_f32_16x16x32_bf16(af[mi], bfv[ni], acc[mi][ni], 0, 0, 0);
    }

#pragma unroll
    for (int mi = 0; mi < 4; ++mi) {
        const int mg = mbase + wm + mi * 16 + g * 4;
#pragma unroll
        for (int ni = 0; ni < 4; ++ni) {
            const int ng = nbase + wn + ni * 16 + lr;
            if constexpr (MODE == 0) {
                const int which = ng >> 10;
                const int nin = ng & 1023;
                const float bias = (which == 0) ? b0[nin] : (which == 1) ? b1[nin] : b2[nin];
                const int h = nin >> 6, d = nin & 63;
                const int b = mg >> 11, t = mg & 2047;
                if (which == 2) {
                    u16x4 pv = { f2bf(acc[mi][ni][0] + bias), f2bf(acc[mi][ni][1] + bias),
                                 f2bf(acc[mi][ni][2] + bias), f2bf(acc[mi][ni][3] + bias) };
                    *reinterpret_cast<u16x4*>(vto + ((size_t)((b * 16 + h) * 64 + d)) * 2048 + t) = pv;
                } else if (which == 0) {
#pragma unroll
                    for (int r = 0; r < 4; ++r)
                        qo[((size_t)(b * 16 + h) * 2048 + (t + r)) * 64 + d] =
                            f2bf((acc[mi][ni][r] + bias) * QSCALE);
                } else {
#pragma unroll
                    for (int r = 0; r < 4; ++r)
                        ko[((size_t)(b * 16 + h) * 2048 + (t + r)) * 64 + d] = f2bf(acc[mi][ni][r] + bias);
                }
            } else {
                const float bias = bp[ng];
#pragma unroll
                for (int r = 0; r < 4; ++r)
                    fout[(size_t)(mg + r) * 1024 + ng] = acc[mi][ni][r] + bias;
            }
        }
    }
}

// ---------------- flash attention v3 (unchanged this round) ----------------
__launch_bounds__(256, 2)
__global__ void attn_k(const unsigned short* __restrict__ qg,
                       const unsigned short* __restrict__ kg,
                       const unsigned short* __restrict__ vtg,
                       unsigned short* __restrict__ og)
{
    __shared__ unsigned short Kt[2][64 * 64];   // [buf][key][d], chunks XOR-swizzled
    __shared__ unsigned short Vs[2][64 * 64];   // [buf][d][key], chunks XOR-swizzled
    __shared__ unsigned short P_lds[4][32 * 64];

    const int pr = blockIdx.x;        // 0..7
    const int bh = blockIdx.y;
    const int b = bh >> 4, h = bh & 15;
    const int tid = threadIdx.x;
    const int w = tid >> 6;
    const int lane = tid & 63;
    const int g = lane >> 4;
    const int lr = lane & 15;

    const unsigned short* Qp = qg + (size_t)bh * TB * 64;
    const unsigned short* Kp = kg + (size_t)bh * TB * 64;
    const unsigned short* Vt = vtg + (size_t)bh * 64 * TB;
    unsigned short* Pw = P_lds[w];

    const int srow = lane >> 3;
    const int schk = lane & 7;
    const int gchk = schk ^ srow;
    const int seg0 = w * 2, seg1 = w * 2 + 1;
    const int swz = (lr & 7);          // read-side XOR

#pragma unroll 1
    for (int half = 0; half < 2; ++half) {
        const int sup = half == 0 ? pr : 15 - pr;
        const int qw = sup * 128 + w * 32;
        const int ntw = (qw >> 6) + 1;       // this wave's causal tile count
        const int NT = sup * 2 + 2;          // block-max tile count (uniform)

        s16x8 bq0[2], bq1[2];
#pragma unroll
        for (int qf = 0; qf < 2; ++qf) {
            const unsigned short* qp = Qp + (size_t)(qw + qf * 16 + lr) * 64 + g * 8;
            bq0[qf] = *reinterpret_cast<const s16x8*>(qp);
            bq1[qf] = *reinterpret_cast<const s16x8*>(qp + 32);
        }

        f32x4 oacc[4][2];
#pragma unroll
        for (int dt = 0; dt < 4; ++dt)
#pragma unroll
            for (int qf = 0; qf < 2; ++qf) oacc[dt][qf] = (f32x4)0.0f;
        float mi_[2] = { -INFINITY, -INFINITY };
        float li_[2] = { 0.0f, 0.0f };

        asm volatile("s_waitcnt lgkmcnt(0)" ::: "memory");
        __builtin_amdgcn_s_barrier();
        {
            gl_lds16(Kp + (size_t)(seg0 * 8 + srow) * 64 + gchk * 8, &Kt[0][seg0 * 512]);
            gl_lds16(Kp + (size_t)(seg1 * 8 + srow) * 64 + gchk * 8, &Kt[0][seg1 * 512]);
            gl_lds16(Vt + (size_t)(seg0 * 8 + srow) * TB + gchk * 8, &Vs[0][seg0 * 512]);
            gl_lds16(Vt + (size_t)(seg1 * 8 + srow) * TB + gchk * 8, &Vs[0][seg1 * 512]);
        }
        asm volatile("s_waitcnt vmcnt(0)" ::: "memory");
        __builtin_amdgcn_s_barrier();
        asm volatile("" ::: "memory");
        __builtin_amdgcn_sched_barrier(0);

        int cur = 0;
#pragma unroll 1
        for (int t = 0; t < NT; ++t) {
            const int other = cur ^ 1;
            if (t > 0) {
                asm volatile("s_waitcnt lgkmcnt(0)" ::: "memory");
                __builtin_amdgcn_s_barrier();
            }
            if (t + 1 < NT) {
                const int k0n = (t + 1) * 64;
                gl_lds16(Kp + (size_t)(k0n + seg0 * 8 + srow) * 64 + gchk * 8, &Kt[other][seg0 * 512]);
                gl_lds16(Kp + (size_t)(k0n + seg1 * 8 + srow) * 64 + gchk * 8, &Kt[other][seg1 * 512]);
                gl_lds16(Vt + (size_t)(seg0 * 8 + srow) * TB + k0n + gchk * 8, &Vs[other][seg0 * 512]);
                gl_lds16(Vt + (size_t)(seg1 * 8 + srow) * TB + k0n + gchk * 8, &Vs[other][seg1 * 512]);
                asm volatile("s_waitcnt vmcnt(4)" ::: "memory");
            } else {
                asm volatile("s_waitcnt vmcnt(0)" ::: "memory");
            }
            __builtin_amdgcn_s_barrier();
            asm volatile("" ::: "memory");
            __builtin_amdgcn_sched_barrier(0);

            if (t < ntw) {
                const unsigned short* Kc = Kt[cur];
                const unsigned short* Vc = Vs[cur];
                f32x4 st[4][2];
#pragma unroll
                for (int sub = 0; sub < 4; ++sub) {
                    const unsigned short* krow = Kc + (sub * 16 + lr) * 64;
                    s16x8 ak0 = *reinterpret_cast<const s16x8*>(krow + ((g ^ swz) * 8));
                    s16x8 ak1 = *reinterpret_cast<const s16x8*>(krow + (((g + 4) ^ swz) * 8));
#pragma unroll
                    for (int qf = 0; qf < 2; ++qf) {
                        f32x4 z = (f32x4)0.0f;
                        z = __builtin_amdgcn_mfma_f32_16x16x32_bf16(ak0, bq0[qf], z, 0, 0, 0);
                        st[sub][qf] = __builtin_amdgcn_mfma_f32_16x16x32_bf16(ak1, bq1[qf], z, 0, 0, 0);
                    }
                }
                if (t == ntw - 1) {
                    const int k0 = t * 64;
#pragma unroll
                    for (int sub = 0; sub < 4; ++sub)
#pragma unroll
                        for (int qf = 0; qf < 2; ++qf)
#pragma unroll
                            for (int r = 0; r < 4; ++r) {
                                const int key = k0 + sub * 16 + g * 4 + r;
                                const int q = qw + qf * 16 + lr;
                                if (key > q) st[sub][qf][r] = -INFINITY;
                            }
                }
                float alpha[2];
#pragma unroll
                for (int qf = 0; qf < 2; ++qf) {
                    float mloc = st[0][qf][0];
#pragma unroll
                    for (int sub = 0; sub < 4; ++sub)
#pragma unroll
                        for (int r = 0; r < 4; ++r) mloc = fmaxf(mloc, st[sub][qf][r]);
                    mloc = fmaxf(mloc, __shfl_xor(mloc, 16));
                    mloc = fmaxf(mloc, __shfl_xor(mloc, 32));
                    const float mn = fmaxf(mi_[qf], mloc);
                    alpha[qf] = __expf(mi_[qf] - mn);
                    mi_[qf] = mn;
                    float ps = 0.0f;
#pragma unroll
                    for (int sub = 0; sub < 4; ++sub)
#pragma unroll
                        for (int r = 0; r < 4; ++r) {
                            const float p = __expf(st[sub][qf][r] - mn);
                            st[sub][qf][r] = p;
                            ps += p;
                        }
                    ps += __shfl_xor(ps, 16);
                    ps += __shfl_xor(ps, 32);
                    li_[qf] = li_[qf] * alpha[qf] + ps;
                }
#pragma unroll
                for (int dt = 0; dt < 4; ++dt)
#pragma unroll
                    for (int qf = 0; qf < 2; ++qf) oacc[dt][qf] *= alpha[qf];
#pragma unroll
                for (int sub = 0; sub < 4; ++sub)
#pragma unroll
                    for (int qf = 0; qf < 2; ++qf) {
                        u16x4 pk = { f2bf(st[sub][qf][0]), f2bf(st[sub][qf][1]),
                                     f2bf(st[sub][qf][2]), f2bf(st[sub][qf][3]) };
                        const int row = qf * 16 + lr;
                        const int bo = sub * 32 + g * 8;
                        const int phys = ((bo >> 4) ^ (row & 7)) * 16 + (bo & 15);
                        *reinterpret_cast<u16x4*>(reinterpret_cast<char*>(Pw + row * 64) + phys) = pk;
                    }
                s16x8 vf[8];
#pragma unroll
                for (int dt = 0; dt < 4; ++dt)
#pragma unroll
                    for (int ks = 0; ks < 2; ++ks)
                        vf[dt * 2 + ks] = *reinterpret_cast<const s16x8*>(
                            Vc + (dt * 16 + lr) * 64 + (((ks * 4 + g) ^ swz) * 8));
#pragma unroll
                for (int qf = 0; qf < 2; ++qf)
#pragma unroll
                    for (int ks = 0; ks < 2; ++ks) {
                        const int row = qf * 16 + lr;
                        const int gran = (ks * 4 + g) ^ (row & 7);
                        s16x8 pb = *reinterpret_cast<const s16x8*>(
                            reinterpret_cast<const char*>(Pw + row * 64) + gran * 16);
#pragma unroll
                        for (int dt = 0; dt < 4; ++dt)
                            oacc[dt][qf] = __builtin_amdgcn_mfma_f32_16x16x32_bf16(vf[dt * 2 + ks], pb, oacc[dt][qf], 0, 0, 0);
                    }
            }
            cur = other;
        }

#pragma unroll
        for (int qf = 0; qf < 2; ++qf) {
            const float inv_l = 1.0f / li_[qf];
            unsigned short* orow = og + ((size_t)(b * TB + qw + qf * 16 + lr)) * CD + h * 64;
#pragma unroll
            for (int dt = 0; dt < 4; ++dt) {
                u16x4 ov = { f2bf(oacc[dt][qf][0] * inv_l), f2bf(oacc[dt][qf][1] * inv_l),
                             f2bf(oacc[dt][qf][2] * inv_l), f2bf(oacc[dt][qf][3] * inv_l) };
                *reinterpret_cast<u16x4*>(orow + dt * 16 + g * 4) = ov;
            }
        }
    }
}

extern "C" void kernel_launch(void* const* d_in, const int* in_sizes, int n_in,
                              void* d_out, int out_size, void* d_ws, size_t ws_size,
                              hipStream_t stream)
{
    const float* x  = (const float*)d_in[0];
    const float* wq = (const float*)d_in[1];
    const float* bq = (const float*)d_in[2];
    const float* wk = (const float*)d_in[3];
    const float* bk = (const float*)d_in[4];
    const float* wv = (const float*)d_in[5];
    const float* bv = (const float*)d_in[6];
    const float* wp = (const float*)d_in[7];
    const float* bp = (const float*)d_in[8];
    float* out = (float*)d_out;

    // workspace (ushort elems), peak 75.5 MB; ob aliases xb (x dead after gemm<0>)
    unsigned short* xb   = (unsigned short*)d_ws;      // 8388608 (x bf16 / attn out)
    unsigned short* wcat = xb + 8388608;               // 3145728 (wq|wk|wv)
    unsigned short* wpb  = wcat + 3145728;             // 1048576
    unsigned short* qb_  = wpb + 1048576;              // 8388608 (B,H,T,HD) pre-scaled
    unsigned short* kb_  = qb_ + 8388608;              // 8388608 (B,H,T,HD)
    unsigned short* vtb  = kb_ + 8388608;              // 8388608 (B,H,HD,T)
    unsigned short* ob   = xb;                         // alias

    cast_k<<<8192, 256, 0, stream>>>(x, xb, 2097152);
    cast_k<<<1024, 256, 0, stream>>>(wq, wcat, 262144);
    cast_k<<<1024, 256, 0, stream>>>(wk, wcat + 1048576, 262144);
    cast_k<<<1024, 256, 0, stream>>>(wv, wcat + 2097152, 262144);
    cast_k<<<1024, 256, 0, stream>>>(wp, wpb, 262144);

    gemm_bt<0><<<dim3(24, 64), 256, 0, stream>>>(xb, wcat, qb_, kb_, vtb,
                                                 bq, bk, bv, nullptr, nullptr);
    attn_k<<<dim3(8, 64), 256, 0, stream>>>(qb_, kb_, vtb, ob);
    gemm_bt<1><<<dim3(8, 64), 256, 0, stream>>>(ob, wpb, nullptr, nullptr, nullptr,
                                                nullptr, nullptr, nullptr, out, bp);
}

// Round 11
// 274.763 us; speedup vs baseline: 2.4376x; 1.0927x over previous
//
#include <hip/hip_runtime.h>
#include <hip/hip_bf16.h>
#include <stdint.h>
#include <math.h>

#define TB 2048
#define CD 1024

typedef short s16x8 __attribute__((ext_vector_type(8)));
typedef unsigned short u16x4 __attribute__((ext_vector_type(4)));
typedef float f32x4 __attribute__((ext_vector_type(4)));

#define QSCALE 0.02209708691207961f  /* 1/sqrt(2048): ref scales by 1/sqrt(T) */

// hardware cast (compiler emits v_cvt_pk_bf16_f32 for adjacent pairs; m240)
__device__ __forceinline__ unsigned short f2bf(float f) {
    __hip_bfloat16 h = __float2bfloat16(f);
    return reinterpret_cast<unsigned short&>(h);
}

// async global->LDS, 16B per lane; dest = wave-uniform base + lane*16 (HW rule)
__device__ __forceinline__ void gl_lds16(const void* g, void* l) {
    typedef const __attribute__((address_space(1))) unsigned int gu32;
    typedef __attribute__((address_space(3))) unsigned int lu32;
    __builtin_amdgcn_global_load_lds((gu32*)g, (lu32*)l, 16, 0, 0);
}

// ---------------- cast fp32 -> bf16 (vectorized x4) ----------------
__global__ void cast_k(const float* __restrict__ src, unsigned short* __restrict__ dst, int n4) {
    int i = blockIdx.x * blockDim.x + threadIdx.x;
    if (i < n4) {
        float4 v = reinterpret_cast<const float4*>(src)[i];
        u16x4 o = { f2bf(v.x), f2bf(v.y), f2bf(v.z), f2bf(v.w) };
        reinterpret_cast<u16x4*>(dst)[i] = o;
    }
}

// ---------------- GEMM C = A(M,K) * Bw(N,K)^T  (m97 structure, unchanged) ----------------
template<int MODE>
__launch_bounds__(256)
__global__ void gemm_bt(const unsigned short* __restrict__ A,
                        const unsigned short* __restrict__ Bw,
                        unsigned short* __restrict__ qo,
                        unsigned short* __restrict__ ko,
                        unsigned short* __restrict__ vto,
                        const float* __restrict__ b0,
                        const float* __restrict__ b1,
                        const float* __restrict__ b2,
                        float* __restrict__ fout,
                        const float* __restrict__ bp)
{
    __shared__ unsigned short As[128 * 32];   // linear: row*32 + col (gl_lds dest)
    __shared__ unsigned short Bs[128 * 32];
    const int tid = threadIdx.x;
    const int mbase = blockIdx.y * 128;
    const int nbase = blockIdx.x * 128;
    const int lane = tid & 63;
    const int w = tid >> 6;
    const int g = lane >> 4;
    const int lr = lane & 15;
    const int wm = (w >> 1) * 64;
    const int wn = (w & 1) * 64;
    const int srow = lane >> 2;          // 0..15
    const int scol = (lane & 3) * 8;     // ushort col: 0,8,16,24

    f32x4 acc[4][4];
#pragma unroll
    for (int i = 0; i < 4; ++i)
#pragma unroll
        for (int j = 0; j < 4; ++j) acc[i][j] = (f32x4)0.0f;

    const size_t arow0 = (size_t)(mbase + w * 16 + srow);
    const size_t arow1 = (size_t)(mbase + 64 + w * 16 + srow);
    const size_t brow0 = (size_t)(nbase + w * 16 + srow);
    const size_t brow1 = (size_t)(nbase + 64 + w * 16 + srow);
    unsigned short* asd0 = As + (w * 16) * 32;
    unsigned short* asd1 = As + (64 + w * 16) * 32;
    unsigned short* bsd0 = Bs + (w * 16) * 32;
    unsigned short* bsd1 = Bs + (64 + w * 16) * 32;

    for (int k0 = 0; k0 < 1024; k0 += 32) {
        __syncthreads();   // all LDS readers of previous tile done
        gl_lds16(A  + arow0 * 1024 + k0 + scol, asd0);
        gl_lds16(A  + arow1 * 1024 + k0 + scol, asd1);
        gl_lds16(Bw + brow0 * 1024 + k0 + scol, bsd0);
        gl_lds16(Bw + brow1 * 1024 + k0 + scol, bsd1);
        __syncthreads();   // compiler drains vmcnt(0) before barrier: tile staged
        s16x8 af[4], bfv[4];
#pragma unroll
        for (int mi = 0; mi < 4; ++mi)
            af[mi] = *reinterpret_cast<const s16x8*>(&As[(wm + mi * 16 + lr) * 32 + g * 8]);
#pragma unroll
        for (int ni = 0; ni < 4; ++ni)
            bfv[ni] = *reinterpret_cast<const s16x8*>(&Bs[(wn + ni * 16 + lr) * 32 + g * 8]);
#pragma unroll
        for (int mi = 0; mi < 4; ++mi)
#pragma unroll
            for (int ni = 0; ni < 4; ++ni)
                acc[mi][ni] = __builtin_amdgcn_mfma_f32_16x16x32_bf16(af[mi], bfv[ni], acc[mi][ni], 0, 0, 0);
    }

#pragma unroll
    for (int mi = 0; mi < 4; ++mi) {
        const int mg = mbase + wm + mi * 16 + g * 4;
#pragma unroll
        for (int ni = 0; ni < 4; ++ni) {
            const int ng = nbase + wn + ni * 16 + lr;
            if constexpr (MODE == 0) {
                const int which = ng >> 10;
                const int nin = ng & 1023;
                const float bias = (which == 0) ? b0[nin] : (which == 1) ? b1[nin] : b2[nin];
                const int h = nin >> 6, d = nin & 63;
                const int b = mg >> 11, t = mg & 2047;
                if (which == 2) {
                    u16x4 pv = { f2bf(acc[mi][ni][0] + bias), f2bf(acc[mi][ni][1] + bias),
                                 f2bf(acc[mi][ni][2] + bias), f2bf(acc[mi][ni][3] + bias) };
                    *reinterpret_cast<u16x4*>(vto + ((size_t)((b * 16 + h) * 64 + d)) * 2048 + t) = pv;
                } else if (which == 0) {
#pragma unroll
                    for (int r = 0; r < 4; ++r)
                        qo[((size_t)(b * 16 + h) * 2048 + (t + r)) * 64 + d] =
                            f2bf((acc[mi][ni][r] + bias) * QSCALE);
                } else {
#pragma unroll
                    for (int r = 0; r < 4; ++r)
                        ko[((size_t)(b * 16 + h) * 2048 + (t + r)) * 64 + d] = f2bf(acc[mi][ni][r] + bias);
                }
            } else {
                const float bias = bp[ng];
#pragma unroll
                for (int r = 0; r < 4; ++r)
                    fout[(size_t)(mg + r) * 1024 + ng] = acc[mi][ni][r] + bias;
            }
        }
    }
}

// ---------------- flash attention v4: 8 waves x 16 q-rows ----------------
// grid (8, 64), 512 threads. Block pairs q-supers p and 15-p (34 tiles const).
// K/V 64-key tiles double-buffered in LDS via global_load_lds(16B), counted
// vmcnt(2) steady state (T3/T4). XOR chunk swizzle via pre-permuted global
// source + swizzled ds_read (rule #21). Per wave: 16 q-rows; S^T = K*Q^T
// (lane owns q-col lr), softmax local+2 shfl + defer-max THR=8 (T13);
// P via per-wave swizzled LDS roundtrip; O^T = V^T * P^T.
__launch_bounds__(512, 4)
__global__ void attn_k(const unsigned short* __restrict__ qg,
                       const unsigned short* __restrict__ kg,
                       const unsigned short* __restrict__ vtg,
                       unsigned short* __restrict__ og)
{
    __shared__ unsigned short Kt[2][64 * 64];   // [buf][key][d], chunks XOR-swizzled
    __shared__ unsigned short Vs[2][64 * 64];   // [buf][d][key], chunks XOR-swizzled
    __shared__ unsigned short P_lds[8][16 * 64];

    const int pr = blockIdx.x;        // 0..7
    const int bh = blockIdx.y;
    const int b = bh >> 4, h = bh & 15;
    const int tid = threadIdx.x;
    const int w = tid >> 6;           // 0..7
    const int lane = tid & 63;
    const int g = lane >> 4;
    const int lr = lane & 15;

    const unsigned short* Qp = qg + (size_t)bh * TB * 64;
    const unsigned short* Kp = kg + (size_t)bh * TB * 64;
    const unsigned short* Vt = vtg + (size_t)bh * 64 * TB;
    unsigned short* Pw = P_lds[w];

    // staging: wave w stages K-segment w and V-segment w (8 rows x 128B each)
    const int srow = lane >> 3;        // 0..7
    const int schk = lane & 7;
    const int gchk = schk ^ srow;      // pre-XORed global chunk (rule #21)
    const int swz = lr & 7;            // read-side XOR

#pragma unroll 1
    for (int half = 0; half < 2; ++half) {
        const int sup = half == 0 ? pr : 15 - pr;
        const int qw = sup * 128 + w * 16;   // this wave's 16 q-rows
        const int ntw = (qw >> 6) + 1;       // causal tile count (this wave)
        const int NT = sup * 2 + 2;          // block-uniform tile count

        const unsigned short* qp = Qp + (size_t)(qw + lr) * 64 + g * 8;
        s16x8 bq0 = *reinterpret_cast<const s16x8*>(qp);
        s16x8 bq1 = *reinterpret_cast<const s16x8*>(qp + 32);

        f32x4 oacc[4];
#pragma unroll
        for (int dt = 0; dt < 4; ++dt) oacc[dt] = (f32x4)0.0f;
        float mi_ = -INFINITY, li_ = 0.0f;

        // ---- prologue: drain prev-half readers, stage tile 0 ----
        asm volatile("s_waitcnt lgkmcnt(0)" ::: "memory");
        __builtin_amdgcn_s_barrier();
        gl_lds16(Kp + (size_t)(w * 8 + srow) * 64 + gchk * 8, &Kt[0][w * 512]);
        gl_lds16(Vt + (size_t)(w * 8 + srow) * TB + gchk * 8, &Vs[0][w * 512]);
        asm volatile("s_waitcnt vmcnt(0)" ::: "memory");
        __builtin_amdgcn_s_barrier();
        asm volatile("" ::: "memory");
        __builtin_amdgcn_sched_barrier(0);

        int cur = 0;
#pragma unroll 1
        for (int t = 0; t < NT; ++t) {
            const int other = cur ^ 1;
            if (t > 0) {
                asm volatile("s_waitcnt lgkmcnt(0)" ::: "memory");
                __builtin_amdgcn_s_barrier();   // buffer 'other' free to overwrite
            }
            if (t + 1 < NT) {
                const int k0n = (t + 1) * 64;
                gl_lds16(Kp + (size_t)(k0n + w * 8 + srow) * 64 + gchk * 8, &Kt[other][w * 512]);
                gl_lds16(Vt + (size_t)(w * 8 + srow) * TB + k0n + gchk * 8, &Vs[other][w * 512]);
                asm volatile("s_waitcnt vmcnt(2)" ::: "memory");   // tile-t landed; t+1 in flight
            } else {
                asm volatile("s_waitcnt vmcnt(0)" ::: "memory");
            }
            __builtin_amdgcn_s_barrier();       // tile-t staged for all waves
            asm volatile("" ::: "memory");
            __builtin_amdgcn_sched_barrier(0);

            if (t < ntw) {
                const unsigned short* Kc = Kt[cur];
                const unsigned short* Vc = Vs[cur];
                // ---- S^T = K * Q^T ----
                f32x4 st[4];
#pragma unroll
                for (int sub = 0; sub < 4; ++sub) {
                    const unsigned short* krow = Kc + (sub * 16 + lr) * 64;
                    s16x8 ak0 = *reinterpret_cast<const s16x8*>(krow + ((g ^ swz) * 8));
                    s16x8 ak1 = *reinterpret_cast<const s16x8*>(krow + (((g + 4) ^ swz) * 8));
                    f32x4 z = (f32x4)0.0f;
                    z = __builtin_amdgcn_mfma_f32_16x16x32_bf16(ak0, bq0, z, 0, 0, 0);
                    st[sub] = __builtin_amdgcn_mfma_f32_16x16x32_bf16(ak1, bq1, z, 0, 0, 0);
                }
                if (t == ntw - 1) {  // causal boundary tile (wave-uniform branch)
                    const int k0 = t * 64;
#pragma unroll
                    for (int sub = 0; sub < 4; ++sub)
#pragma unroll
                        for (int r = 0; r < 4; ++r) {
                            const int key = k0 + sub * 16 + g * 4 + r;
                            if (key > qw + lr) st[sub][r] = -INFINITY;
                        }
                }
                // ---- online softmax + defer-max (T13, THR=8) ----
                float mloc = st[0][0];
#pragma unroll
                for (int sub = 0; sub < 4; ++sub)
#pragma unroll
                    for (int r = 0; r < 4; ++r) mloc = fmaxf(mloc, st[sub][r]);
                mloc = fmaxf(mloc, __shfl_xor(mloc, 16));
                mloc = fmaxf(mloc, __shfl_xor(mloc, 32));
                if (__any(mloc - mi_ > 8.0f)) {     // wave-uniform rescale decision
                    const float mn = fmaxf(mi_, mloc);
                    const float alpha = __expf(mi_ - mn);
                    li_ *= alpha;
#pragma unroll
                    for (int dt = 0; dt < 4; ++dt) oacc[dt] *= alpha;
                    mi_ = mn;
                }
                float ps = 0.0f;
#pragma unroll
                for (int sub = 0; sub < 4; ++sub)
#pragma unroll
                    for (int r = 0; r < 4; ++r) {
                        const float p = __expf(st[sub][r] - mi_);   // bounded by e^8
                        st[sub][r] = p;
                        ps += p;
                    }
                ps += __shfl_xor(ps, 16);
                ps += __shfl_xor(ps, 32);
                li_ += ps;
                // ---- P -> per-wave LDS (XOR granule swizzle) ----
#pragma unroll
                for (int sub = 0; sub < 4; ++sub) {
                    u16x4 pk = { f2bf(st[sub][0]), f2bf(st[sub][1]),
                                 f2bf(st[sub][2]), f2bf(st[sub][3]) };
                    const int bo = sub * 32 + g * 8;
                    const int phys = ((bo >> 4) ^ swz) * 16 + (bo & 15);
                    *reinterpret_cast<u16x4*>(reinterpret_cast<char*>(Pw + lr * 64) + phys) = pk;
                }
                // ---- PV: O^T += V^T * P^T (wave-internal DS pipe in-order) ----
#pragma unroll
                for (int ks = 0; ks < 2; ++ks) {
                    const int gran = (ks * 4 + g) ^ swz;
                    s16x8 pb = *reinterpret_cast<const s16x8*>(
                        reinterpret_cast<const char*>(Pw + lr * 64) + gran * 16);
#pragma unroll
                    for (int dt = 0; dt < 4; ++dt) {
                        s16x8 vfr = *reinterpret_cast<const s16x8*>(
                            Vc + (dt * 16 + lr) * 64 + (((ks * 4 + g) ^ swz) * 8));
                        oacc[dt] = __builtin_amdgcn_mfma_f32_16x16x32_bf16(vfr, pb, oacc[dt], 0, 0, 0);
                    }
                }
            }
            cur = other;
        }

        // ---- epilogue: O^T[d][q] -> og[(b*T+q)*C + h*64 + d] ----
        const float inv_l = 1.0f / li_;
        unsigned short* orow = og + ((size_t)(b * TB + qw + lr)) * CD + h * 64;
#pragma unroll
        for (int dt = 0; dt < 4; ++dt) {
            u16x4 ov = { f2bf(oacc[dt][0] * inv_l), f2bf(oacc[dt][1] * inv_l),
                         f2bf(oacc[dt][2] * inv_l), f2bf(oacc[dt][3] * inv_l) };
            *reinterpret_cast<u16x4*>(orow + dt * 16 + g * 4) = ov;
        }
    }
}

extern "C" void kernel_launch(void* const* d_in, const int* in_sizes, int n_in,
                              void* d_out, int out_size, void* d_ws, size_t ws_size,
                              hipStream_t stream)
{
    const float* x  = (const float*)d_in[0];
    const float* wq = (const float*)d_in[1];
    const float* bq = (const float*)d_in[2];
    const float* wk = (const float*)d_in[3];
    const float* bk = (const float*)d_in[4];
    const float* wv = (const float*)d_in[5];
    const float* bv = (const float*)d_in[6];
    const float* wp = (const float*)d_in[7];
    const float* bp = (const float*)d_in[8];
    float* out = (float*)d_out;

    // workspace (ushort elems), peak 75.5 MB; ob aliases xb (x dead after gemm<0>)
    unsigned short* xb   = (unsigned short*)d_ws;      // 8388608 (x bf16 / attn out)
    unsigned short* wcat = xb + 8388608;               // 3145728 (wq|wk|wv)
    unsigned short* wpb  = wcat + 3145728;             // 1048576
    unsigned short* qb_  = wpb + 1048576;              // 8388608 (B,H,T,HD) pre-scaled
    unsigned short* kb_  = qb_ + 8388608;              // 8388608 (B,H,T,HD)
    unsigned short* vtb  = kb_ + 8388608;              // 8388608 (B,H,HD,T)
    unsigned short* ob   = xb;                         // alias

    cast_k<<<8192, 256, 0, stream>>>(x, xb, 2097152);
    cast_k<<<1024, 256, 0, stream>>>(wq, wcat, 262144);
    cast_k<<<1024, 256, 0, stream>>>(wk, wcat + 1048576, 262144);
    cast_k<<<1024, 256, 0, stream>>>(wv, wcat + 2097152, 262144);
    cast_k<<<1024, 256, 0, stream>>>(wp, wpb, 262144);

    gemm_bt<0><<<dim3(24, 64), 256, 0, stream>>>(xb, wcat, qb_, kb_, vtb,
                                                 bq, bk, bv, nullptr, nullptr);
    attn_k<<<dim3(8, 64), 512, 0, stream>>>(qb_, kb_, vtb, ob);
    gemm_bt<1><<<dim3(8, 64), 256, 0, stream>>>(ob, wpb, nullptr, nullptr, nullptr,
                                                nullptr, nullptr, nullptr, out, bp);
}

// Round 14
// 269.028 us; speedup vs baseline: 2.4896x; 1.0213x over previous
//
#include <hip/hip_runtime.h>
#include <hip/hip_bf16.h>
#include <stdint.h>
#include <math.h>

#define TB 2048
#define CD 1024

typedef short s16x8 __attribute__((ext_vector_type(8)));
typedef unsigned short u16x4 __attribute__((ext_vector_type(4)));
typedef float f32x4 __attribute__((ext_vector_type(4)));

#define QSCALE 0.02209708691207961f  /* 1/sqrt(2048): ref scales by 1/sqrt(T) */

// hardware cast (compiler emits v_cvt_pk_bf16_f32 for adjacent pairs; m240)
__device__ __forceinline__ unsigned short f2bf(float f) {
    __hip_bfloat16 h = __float2bfloat16(f);
    return reinterpret_cast<unsigned short&>(h);
}

// async global->LDS, 16B per lane; dest = wave-uniform base + lane*16 (HW rule)
__device__ __forceinline__ void gl_lds16(const void* g, void* l) {
    typedef const __attribute__((address_space(1))) unsigned int gu32;
    typedef __attribute__((address_space(3))) unsigned int lu32;
    __builtin_amdgcn_global_load_lds((gu32*)g, (lu32*)l, 16, 0, 0);
}

// ---------------- cast fp32 -> bf16 (vectorized x4) ----------------
__global__ void cast_k(const float* __restrict__ src, unsigned short* __restrict__ dst, int n4) {
    int i = blockIdx.x * blockDim.x + threadIdx.x;
    if (i < n4) {
        float4 v = reinterpret_cast<const float4*>(src)[i];
        u16x4 o = { f2bf(v.x), f2bf(v.y), f2bf(v.z), f2bf(v.w) };
        reinterpret_cast<u16x4*>(dst)[i] = o;
    }
}

// ---------------- GEMM C = A(M,K) * Bw(N,K)^T ----------------
// m97 structure, BK=64: 128x128 tile, LDS [128][64] staged via global_load_lds
// with both-sides 16B-chunk XOR swizzle (LDS[row][c] = G[row][c^(row&7)]);
// fragment reads at ((kk*4+g)^(lr&7)) -> 2 lanes/bank (free, m136). 16 K-iters,
// 2 barriers each (half the barrier drains of BK=32). 4 waves, 64x64 out each.
template<int MODE>
__launch_bounds__(256)
__global__ void gemm_bt(const unsigned short* __restrict__ A,
                        const unsigned short* __restrict__ Bw,
                        unsigned short* __restrict__ qo,
                        unsigned short* __restrict__ ko,
                        unsigned short* __restrict__ vto,
                        const float* __restrict__ b0,
                        const float* __restrict__ b1,
                        const float* __restrict__ b2,
                        float* __restrict__ fout,
                        const float* __restrict__ bp)
{
    __shared__ unsigned short As[128 * 64];   // 16 KB each
    __shared__ unsigned short Bs[128 * 64];
    const int tid = threadIdx.x;
    const int mbase = blockIdx.y * 128;
    const int nbase = blockIdx.x * 128;
    const int lane = tid & 63;
    const int w = tid >> 6;
    const int g = lane >> 4;
    const int lr = lane & 15;
    const int wm = (w >> 1) * 64;
    const int wn = (w & 1) * 64;
    // staging: wave w stages rows [w*32, w*32+32) in 4 instr (8 rows each).
    // lane -> row lane>>3, chunk lane&7; source chunk pre-XORed (rule #21).
    const int srow8 = lane >> 3;          // 0..7
    const int gchk = (lane & 7) ^ srow8;  // global 16B-chunk index

    f32x4 acc[4][4];
#pragma unroll
    for (int i = 0; i < 4; ++i)
#pragma unroll
        for (int j = 0; j < 4; ++j) acc[i][j] = (f32x4)0.0f;

    const unsigned short* Arow = A  + (size_t)(mbase + w * 32 + srow8) * 1024 + gchk * 8;
    const unsigned short* Brow = Bw + (size_t)(nbase + w * 32 + srow8) * 1024 + gchk * 8;
    unsigned short* asd = As + (w * 32) * 64;
    unsigned short* bsd = Bs + (w * 32) * 64;
    const int xswz = lr & 7;   // read-side XOR (row&7 == lr&7 for fragment rows)

    for (int k0 = 0; k0 < 1024; k0 += 64) {
        __syncthreads();   // all LDS readers of previous tile done
#pragma unroll
        for (int i = 0; i < 4; ++i) {
            gl_lds16(Arow + (size_t)(i * 8) * 1024 + k0, asd + i * 8 * 64);
            gl_lds16(Brow + (size_t)(i * 8) * 1024 + k0, bsd + i * 8 * 64);
        }
        __syncthreads();   // compiler drains vmcnt(0) before barrier: tile staged
#pragma unroll
        for (int kk = 0; kk < 2; ++kk) {
            const int xr = ((kk * 4 + g) ^ xswz) * 8;
            s16x8 af[4], bfv[4];
#pragma unroll
            for (int mi = 0; mi < 4; ++mi)
                af[mi] = *reinterpret_cast<const s16x8*>(&As[(wm + mi * 16 + lr) * 64 + xr]);
#pragma unroll
            for (int ni = 0; ni < 4; ++ni)
                bfv[ni] = *reinterpret_cast<const s16x8*>(&Bs[(wn + ni * 16 + lr) * 64 + xr]);
#pragma unroll
            for (int mi = 0; mi < 4; ++mi)
#pragma unroll
                for (int ni = 0; ni < 4; ++ni)
                    acc[mi][ni] = __builtin_amdgcn_mfma_f32_16x16x32_bf16(af[mi], bfv[ni], acc[mi][ni], 0, 0, 0);
        }
    }

#pragma unroll
    for (int mi = 0; mi < 4; ++mi) {
        const int mg = mbase + wm + mi * 16 + g * 4;
#pragma unroll
        for (int ni = 0; ni < 4; ++ni) {
            const int ng = nbase + wn + ni * 16 + lr;
            if constexpr (MODE == 0) {
                const int which = ng >> 10;
                const int nin = ng & 1023;
                const float bias = (which == 0) ? b0[nin] : (which == 1) ? b1[nin] : b2[nin];
                const int h = nin >> 6, d = nin & 63;
                const int b = mg >> 11, t = mg & 2047;
                if (which == 2) {
                    u16x4 pv = { f2bf(acc[mi][ni][0] + bias), f2bf(acc[mi][ni][1] + bias),
                                 f2bf(acc[mi][ni][2] + bias), f2bf(acc[mi][ni][3] + bias) };
                    *reinterpret_cast<u16x4*>(vto + ((size_t)((b * 16 + h) * 64 + d)) * 2048 + t) = pv;
                } else if (which == 0) {
#pragma unroll
                    for (int r = 0; r < 4; ++r)
                        qo[((size_t)(b * 16 + h) * 2048 + (t + r)) * 64 + d] =
                            f2bf((acc[mi][ni][r] + bias) * QSCALE);
                } else {
#pragma unroll
                    for (int r = 0; r < 4; ++r)
                        ko[((size_t)(b * 16 + h) * 2048 + (t + r)) * 64 + d] = f2bf(acc[mi][ni][r] + bias);
                }
            } else {
                const float bias = bp[ng];
#pragma unroll
                for (int r = 0; r < 4; ++r)
                    fout[(size_t)(mg + r) * 1024 + ng] = acc[mi][ni][r] + bias;
            }
        }
    }
}

// ---------------- flash attention v4.1: 8 waves x 16 q-rows + T5/T17 ----------------
__launch_bounds__(512, 4)
__global__ void attn_k(const unsigned short* __restrict__ qg,
                       const unsigned short* __restrict__ kg,
                       const unsigned short* __restrict__ vtg,
                       unsigned short* __restrict__ og)
{
    __shared__ unsigned short Kt[2][64 * 64];   // [buf][key][d], chunks XOR-swizzled
    __shared__ unsigned short Vs[2][64 * 64];   // [buf][d][key], chunks XOR-swizzled
    __shared__ unsigned short P_lds[8][16 * 64];

    const int pr = blockIdx.x;        // 0..7
    const int bh = blockIdx.y;
    const int b = bh >> 4, h = bh & 15;
    const int tid = threadIdx.x;
    const int w = tid >> 6;           // 0..7
    const int lane = tid & 63;
    const int g = lane >> 4;
    const int lr = lane & 15;

    const unsigned short* Qp = qg + (size_t)bh * TB * 64;
    const unsigned short* Kp = kg + (size_t)bh * TB * 64;
    const unsigned short* Vt = vtg + (size_t)bh * 64 * TB;
    char* prow = reinterpret_cast<char*>(&P_lds[w][lr * 64]);

    const int srow = lane >> 3;        // 0..7
    const int gchk = (lane & 7) ^ srow;
    const int swz = lr & 7;

#pragma unroll 1
    for (int half = 0; half < 2; ++half) {
        const int sup = half == 0 ? pr : 15 - pr;
        const int qw = sup * 128 + w * 16;
        const int ntw = (qw >> 6) + 1;
        const int NT = sup * 2 + 2;

        const unsigned short* qp = Qp + (size_t)(qw + lr) * 64 + g * 8;
        s16x8 bq0 = *reinterpret_cast<const s16x8*>(qp);
        s16x8 bq1 = *reinterpret_cast<const s16x8*>(qp + 32);

        f32x4 oacc[4];
#pragma unroll
        for (int dt = 0; dt < 4; ++dt) oacc[dt] = (f32x4)0.0f;
        float mi_ = -INFINITY, li_ = 0.0f;

        asm volatile("s_waitcnt lgkmcnt(0)" ::: "memory");
        __builtin_amdgcn_s_barrier();
        gl_lds16(Kp + (size_t)(w * 8 + srow) * 64 + gchk * 8, &Kt[0][w * 512]);
        gl_lds16(Vt + (size_t)(w * 8 + srow) * TB + gchk * 8, &Vs[0][w * 512]);
        asm volatile("s_waitcnt vmcnt(0)" ::: "memory");
        __builtin_amdgcn_s_barrier();
        asm volatile("" ::: "memory");
        __builtin_amdgcn_sched_barrier(0);

        int cur = 0;
#pragma unroll 1
        for (int t = 0; t < NT; ++t) {
            const int other = cur ^ 1;
            if (t > 0) {
                asm volatile("s_waitcnt lgkmcnt(0)" ::: "memory");
                __builtin_amdgcn_s_barrier();
            }
            if (t + 1 < NT) {
                const int k0n = (t + 1) * 64;
                gl_lds16(Kp + (size_t)(k0n + w * 8 + srow) * 64 + gchk * 8, &Kt[other][w * 512]);
                gl_lds16(Vt + (size_t)(w * 8 + srow) * TB + k0n + gchk * 8, &Vs[other][w * 512]);
                asm volatile("s_waitcnt vmcnt(2)" ::: "memory");
            } else {
                asm volatile("s_waitcnt vmcnt(0)" ::: "memory");
            }
            __builtin_amdgcn_s_barrier();
            asm volatile("" ::: "memory");
            __builtin_amdgcn_sched_barrier(0);

            if (t < ntw) {
                const unsigned short* Kc = Kt[cur];
                const unsigned short* Vc = Vs[cur];
                // ---- S^T = K * Q^T (T5: boost wave while MFMA-issuing) ----
                f32x4 st[4];
                __builtin_amdgcn_s_setprio(1);
#pragma unroll
                for (int sub = 0; sub < 4; ++sub) {
                    const unsigned short* krow = Kc + (sub * 16 + lr) * 64;
                    s16x8 ak0 = *reinterpret_cast<const s16x8*>(krow + ((g ^ swz) * 8));
                    s16x8 ak1 = *reinterpret_cast<const s16x8*>(krow + (((g + 4) ^ swz) * 8));
                    f32x4 z = (f32x4)0.0f;
                    z = __builtin_amdgcn_mfma_f32_16x16x32_bf16(ak0, bq0, z, 0, 0, 0);
                    st[sub] = __builtin_amdgcn_mfma_f32_16x16x32_bf16(ak1, bq1, z, 0, 0, 0);
                }
                __builtin_amdgcn_s_setprio(0);
                if (t == ntw - 1) {  // causal boundary tile (wave-uniform branch)
                    const int k0 = t * 64;
#pragma unroll
                    for (int sub = 0; sub < 4; ++sub)
#pragma unroll
                        for (int r = 0; r < 4; ++r) {
                            const int key = k0 + sub * 16 + g * 4 + r;
                            if (key > qw + lr) st[sub][r] = -INFINITY;
                        }
                }
                // ---- online softmax: max-tree (T17-style) + defer-max (T13) ----
                float m0 = fmaxf(fmaxf(st[0][0], st[0][1]), fmaxf(st[0][2], st[0][3]));
                float m1 = fmaxf(fmaxf(st[1][0], st[1][1]), fmaxf(st[1][2], st[1][3]));
                float m2 = fmaxf(fmaxf(st[2][0], st[2][1]), fmaxf(st[2][2], st[2][3]));
                float m3 = fmaxf(fmaxf(st[3][0], st[3][1]), fmaxf(st[3][2], st[3][3]));
                float mloc = fmaxf(fmaxf(m0, m1), fmaxf(m2, m3));
                mloc = fmaxf(mloc, __shfl_xor(mloc, 16));
                mloc = fmaxf(mloc, __shfl_xor(mloc, 32));
                if (__any(mloc - mi_ > 8.0f)) {
                    const float mn = fmaxf(mi_, mloc);
                    const float alpha = __expf(mi_ - mn);
                    li_ *= alpha;
#pragma unroll
                    for (int dt = 0; dt < 4; ++dt) oacc[dt] *= alpha;
                    mi_ = mn;
                }
                float ps = 0.0f;
#pragma unroll
                for (int sub = 0; sub < 4; ++sub)
#pragma unroll
                    for (int r = 0; r < 4; ++r) {
                        const float p = __expf(st[sub][r] - mi_);   // bounded by e^8
                        st[sub][r] = p;
                        ps += p;
                    }
                ps += __shfl_xor(ps, 16);
                ps += __shfl_xor(ps, 32);
                li_ += ps;
                // ---- P -> per-wave LDS (XOR granule swizzle) ----
#pragma unroll
                for (int sub = 0; sub < 4; ++sub) {
                    u16x4 pk = { f2bf(st[sub][0]), f2bf(st[sub][1]),
                                 f2bf(st[sub][2]), f2bf(st[sub][3]) };
                    const int bo = sub * 32 + g * 8;
                    const int phys = ((bo >> 4) ^ swz) * 16 + (bo & 15);
                    *reinterpret_cast<u16x4*>(prow + phys) = pk;
                }
                // ---- PV: O^T += V^T * P^T (T5 around MFMA cluster) ----
                __builtin_amdgcn_s_setprio(1);
#pragma unroll
                for (int ks = 0; ks < 2; ++ks) {
                    const int gran = (ks * 4 + g) ^ swz;
                    s16x8 pb = *reinterpret_cast<const s16x8*>(prow + gran * 16);
#pragma unroll
                    for (int dt = 0; dt < 4; ++dt) {
                        s16x8 vfr = *reinterpret_cast<const s16x8*>(
                            Vc + (dt * 16 + lr) * 64 + (((ks * 4 + g) ^ swz) * 8));
                        oacc[dt] = __builtin_amdgcn_mfma_f32_16x16x32_bf16(vfr, pb, oacc[dt], 0, 0, 0);
                    }
                }
                __builtin_amdgcn_s_setprio(0);
            }
            cur = other;
        }

        const float inv_l = 1.0f / li_;
        unsigned short* orow = og + ((size_t)(b * TB + qw + lr)) * CD + h * 64;
#pragma unroll
        for (int dt = 0; dt < 4; ++dt) {
            u16x4 ov = { f2bf(oacc[dt][0] * inv_l), f2bf(oacc[dt][1] * inv_l),
                         f2bf(oacc[dt][2] * inv_l), f2bf(oacc[dt][3] * inv_l) };
            *reinterpret_cast<u16x4*>(orow + dt * 16 + g * 4) = ov;
        }
    }
}

extern "C" void kernel_launch(void* const* d_in, const int* in_sizes, int n_in,
                              void* d_out, int out_size, void* d_ws, size_t ws_size,
                              hipStream_t stream)
{
    const float* x  = (const float*)d_in[0];
    const float* wq = (const float*)d_in[1];
    const float* bq = (const float*)d_in[2];
    const float* wk = (const float*)d_in[3];
    const float* bk = (const float*)d_in[4];
    const float* wv = (const float*)d_in[5];
    const float* bv = (const float*)d_in[6];
    const float* wp = (const float*)d_in[7];
    const float* bp = (const float*)d_in[8];
    float* out = (float*)d_out;

    // workspace (ushort elems), peak 75.5 MB; ob aliases xb (x dead after gemm<0>)
    unsigned short* xb   = (unsigned short*)d_ws;      // 8388608 (x bf16 / attn out)
    unsigned short* wcat = xb + 8388608;               // 3145728 (wq|wk|wv)
    unsigned short* wpb  = wcat + 3145728;             // 1048576
    unsigned short* qb_  = wpb + 1048576;              // 8388608 (B,H,T,HD) pre-scaled
    unsigned short* kb_  = qb_ + 8388608;              // 8388608 (B,H,T,HD)
    unsigned short* vtb  = kb_ + 8388608;              // 8388608 (B,H,HD,T)
    unsigned short* ob   = xb;                         // alias

    cast_k<<<8192, 256, 0, stream>>>(x, xb, 2097152);
    cast_k<<<1024, 256, 0, stream>>>(wq, wcat, 262144);
    cast_k<<<1024, 256, 0, stream>>>(wk, wcat + 1048576, 262144);
    cast_k<<<1024, 256, 0, stream>>>(wv, wcat + 2097152, 262144);
    cast_k<<<1024, 256, 0, stream>>>(wp, wpb, 262144);

    gemm_bt<0><<<dim3(24, 64), 256, 0, stream>>>(xb, wcat, qb_, kb_, vtb,
                                                 bq, bk, bv, nullptr, nullptr);
    attn_k<<<dim3(8, 64), 512, 0, stream>>>(qb_, kb_, vtb, ob);
    gemm_bt<1><<<dim3(8, 64), 256, 0, stream>>>(ob, wpb, nullptr, nullptr, nullptr,
                                                nullptr, nullptr, nullptr, out, bp);
}